// Round 1
// baseline (1501.095 us; speedup 1.0000x reference)
//
#include <hip/hip_runtime.h>

#define NN 100000
#define NE 1600000
#define DIN 128
#define DC 64

constexpr int SCAN_CHUNK = 2048;
constexpr int NB_SCAN = (NN + SCAN_CHUNK - 1) / SCAN_CHUNK;  // 49

__global__ void zero_u32(unsigned int* p, int n) {
    int i = blockIdx.x * blockDim.x + threadIdx.x;
    if (i < n) p[i] = 0u;
}

__global__ void count_deg(const int* __restrict__ dst, int* __restrict__ deg) {
    int i = blockIdx.x * blockDim.x + threadIdx.x;
    if (i < NE) atomicAdd(&deg[dst[i]], 1);
}

__global__ void scan_partial(const int* __restrict__ deg, int* __restrict__ partial) {
    __shared__ int ls[256];
    int base = blockIdx.x * SCAN_CHUNK;
    int t = threadIdx.x;
    int s = 0;
    for (int j = 0; j < SCAN_CHUNK; j += 256) {
        int i = base + j + t;
        if (i < NN) s += deg[i];
    }
    ls[t] = s;
    __syncthreads();
    for (int off = 128; off > 0; off >>= 1) {
        if (t < off) ls[t] += ls[t + off];
        __syncthreads();
    }
    if (t == 0) partial[blockIdx.x] = ls[0];
}

__global__ void scan_serial(int* partial, int* offsets) {
    if (threadIdx.x == 0) {
        int run = 0;
        for (int b = 0; b < NB_SCAN; ++b) {
            int v = partial[b];
            partial[b] = run;
            run += v;
        }
        offsets[NN] = NE;
    }
}

// Reads deg, writes offsets and cursor. cursor may alias deg (each thread
// reads its own 8 deg values into registers before writing).
__global__ void scan_final(const int* __restrict__ deg, const int* __restrict__ partial,
                           int* __restrict__ offsets, int* __restrict__ cursor) {
    __shared__ int tot[256];
    int t = threadIdx.x;
    int base = blockIdx.x * SCAN_CHUNK + t * 8;
    int d[8];
    int s = 0;
#pragma unroll
    for (int j = 0; j < 8; ++j) {
        int i = base + j;
        d[j] = (i < NN) ? deg[i] : 0;
        s += d[j];
    }
    tot[t] = s;
    __syncthreads();
    int pre = partial[blockIdx.x];
    for (int j = 0; j < t; ++j) pre += tot[j];
#pragma unroll
    for (int j = 0; j < 8; ++j) {
        int i = base + j;
        if (i < NN) {
            offsets[i] = pre;
            cursor[i] = pre;
        }
        pre += d[j];
    }
}

__global__ void scatter_edges(const int* __restrict__ src, const int* __restrict__ dst,
                              int* __restrict__ cursor, int* __restrict__ csr_src) {
    int i = blockIdx.x * blockDim.x + threadIdx.x;
    if (i < NE) {
        int pos = atomicAdd(&cursor[dst[i]], 1);
        csr_src[pos] = src[i];
    }
}

// Y[N,KOUT] = X[N,KIN] @ W[KIN,KOUT] (+ bias). Vector-ALU GEMM, W staged in
// LDS in K-chunks (static LDS kept under 64 KB).
template <int KIN, int KOUT>
__global__ void gemm_kernel(const float* __restrict__ X, const float* __restrict__ W,
                            const float* __restrict__ bias, float* __restrict__ Y) {
    constexpr int TM = 8;
    constexpr int RG = 256 / KOUT;
    constexpr int TROWS = RG * TM;
    constexpr int KCHUNK = (KIN < 64) ? KIN : 64;
    __shared__ float Ws[KCHUNK * KOUT];
    __shared__ float Xs[TROWS * KIN];
    int t = threadIdx.x;
    int rbase = blockIdx.x * TROWS;
    for (int i = t; i < TROWS * KIN; i += 256) {
        int r = i / KIN, k = i % KIN;
        int gr = rbase + r;
        Xs[i] = (gr < NN) ? X[gr * KIN + k] : 0.f;
    }
    int col = t % KOUT;
    int rg = t / KOUT;
    float acc[TM];
#pragma unroll
    for (int m = 0; m < TM; ++m) acc[m] = 0.f;
    for (int kc = 0; kc < KIN; kc += KCHUNK) {
        __syncthreads();
        for (int i = t; i < KCHUNK * KOUT; i += 256) {
            int k = i / KOUT, c2 = i % KOUT;
            Ws[i] = W[(kc + k) * KOUT + c2];
        }
        __syncthreads();
        for (int k = 0; k < KCHUNK; ++k) {
            float w = Ws[k * KOUT + col];
#pragma unroll
            for (int m = 0; m < TM; ++m)
                acc[m] += Xs[(rg * TM + m) * KIN + kc + k] * w;
        }
    }
    float b = bias ? bias[col] : 0.f;
#pragma unroll
    for (int m = 0; m < TM; ++m) {
        int gr = rbase + rg * TM + m;
        if (gr < NN) Y[gr * KOUT + col] = acc[m] + b;
    }
}

// Per-node attention logits: e_src[n,h] = <h[n,h,:], a_src[h,:]>, same for dst.
// One wave per node, lane = channel.
__global__ void att_scores(const float* __restrict__ h, const float* __restrict__ as,
                           const float* __restrict__ ad, float* __restrict__ e_src,
                           float* __restrict__ e_dst) {
    int wave = threadIdx.x >> 6;
    int lane = threadIdx.x & 63;
    int n = blockIdx.x * 4 + wave;
    if (n >= NN) return;
    float h0 = h[n * 128 + lane];
    float h1 = h[n * 128 + 64 + lane];
    float s0 = h0 * as[lane], s1 = h1 * as[64 + lane];
    float d0 = h0 * ad[lane], d1 = h1 * ad[64 + lane];
    for (int off = 32; off > 0; off >>= 1) {
        s0 += __shfl_xor(s0, off, 64);
        s1 += __shfl_xor(s1, off, 64);
        d0 += __shfl_xor(d0, off, 64);
        d1 += __shfl_xor(d1, off, 64);
    }
    if (lane == 0) {
        e_src[n * 2] = s0;
        e_src[n * 2 + 1] = s1;
        e_dst[n * 2] = d0;
        e_dst[n * 2 + 1] = d1;
    }
}

// One wave per destination node. Pass 1: segment max over in-edges (lanes
// stride edges). Pass 2: lane = channel; serial edge loop, coalesced 512B
// feature gathers; softmax-weighted accumulate, then mean-over-heads + bias
// + skip, written pre-BN.
__global__ void aggregate(const int* __restrict__ offsets, const int* __restrict__ csr_src,
                          const float* __restrict__ e_src, const float* __restrict__ e_dst,
                          const float* __restrict__ h, const float* __restrict__ skip,
                          const float* __restrict__ bias, float* __restrict__ hraw) {
    int wave = threadIdx.x >> 6;
    int lane = threadIdx.x & 63;
    int n = blockIdx.x * 4 + wave;
    if (n >= NN) return;
    int beg = offsets[n], end = offsets[n + 1];
    float ed0 = e_dst[n * 2], ed1 = e_dst[n * 2 + 1];
    float m0 = -1e30f, m1 = -1e30f;
    for (int j = beg + lane; j < end; j += 64) {
        int s = csr_src[j];
        float a0 = e_src[s * 2] + ed0;
        float a1 = e_src[s * 2 + 1] + ed1;
        a0 = a0 >= 0.f ? a0 : 0.2f * a0;
        a1 = a1 >= 0.f ? a1 : 0.2f * a1;
        m0 = fmaxf(m0, a0);
        m1 = fmaxf(m1, a1);
    }
    for (int off = 32; off > 0; off >>= 1) {
        m0 = fmaxf(m0, __shfl_xor(m0, off, 64));
        m1 = fmaxf(m1, __shfl_xor(m1, off, 64));
    }
    float acc0 = 0.f, acc1 = 0.f, den0 = 0.f, den1 = 0.f;
    for (int j = beg; j < end; ++j) {
        int s = csr_src[j];  // wave-uniform -> broadcast load
        float a0 = e_src[s * 2] + ed0;
        float a1 = e_src[s * 2 + 1] + ed1;
        a0 = a0 >= 0.f ? a0 : 0.2f * a0;
        a1 = a1 >= 0.f ? a1 : 0.2f * a1;
        float w0 = __expf(a0 - m0), w1 = __expf(a1 - m1);
        den0 += w0;
        den1 += w1;
        acc0 += w0 * h[s * 128 + lane];
        acc1 += w1 * h[s * 128 + 64 + lane];
    }
    float o = 0.5f * (acc0 / (den0 + 1e-16f) + acc1 / (den1 + 1e-16f)) + bias[lane] +
              skip[n * 64 + lane];
    hraw[n * 64 + lane] = o;
}

__global__ void bn_stats(const float* __restrict__ x, float* __restrict__ sums) {
    __shared__ float ls[256], ls2[256];
    int t = threadIdx.x;
    int c = t & 63, q = t >> 6;
    float s = 0.f, s2 = 0.f;
    int rbeg = blockIdx.x * 512;
    for (int r = rbeg + q; r < rbeg + 512; r += 4) {
        if (r < NN) {
            float v = x[r * 64 + c];
            s += v;
            s2 += v * v;
        }
    }
    ls[t] = s;
    ls2[t] = s2;
    __syncthreads();
    if (t < 64) {
        s = ls[t] + ls[t + 64] + ls[t + 128] + ls[t + 192];
        s2 = ls2[t] + ls2[t + 64] + ls2[t + 128] + ls2[t + 192];
        atomicAdd(&sums[c], s);
        atomicAdd(&sums[64 + c], s2);
    }
}

__global__ void bn_final(const float* __restrict__ sums, const float* __restrict__ g,
                         const float* __restrict__ be, float* __restrict__ sc_sh) {
    int c = threadIdx.x;
    if (c < 64) {
        float mu = sums[c] / (float)NN;
        float var = sums[64 + c] / (float)NN - mu * mu;
        float sc = g[c] * rsqrtf(var + 1e-5f);
        sc_sh[c] = sc;
        sc_sh[64 + c] = be[c] - mu * sc;
    }
}

__global__ void bn_norm_jk(const float* __restrict__ hraw, const float* __restrict__ sc_sh,
                           float* __restrict__ xcur, float* __restrict__ jk,
                           float* __restrict__ out) {
    int i = blockIdx.x * blockDim.x + threadIdx.x;
    if (i < NN * 64) {
        int c = i & 63;
        float v = hraw[i] * sc_sh[c] + sc_sh[64 + c];
        v = v >= 0.f ? v : 0.01f * v;
        xcur[i] = v;
        float j = fmaxf(jk[i], v);
        jk[i] = j;
        if (out) out[i] = j;
    }
}

extern "C" void kernel_launch(void* const* d_in, const int* in_sizes, int n_in,
                              void* d_out, int out_size, void* d_ws, size_t ws_size,
                              hipStream_t stream) {
    const float* x = (const float*)d_in[0];
    const int* ei = (const int*)d_in[1];
    const int* e_src_idx = ei;       // row 0: src
    const int* e_dst_idx = ei + NE;  // row 1: dst
    const float* W0 = (const float*)d_in[2];
    const float* as0 = (const float*)d_in[3];
    const float* ad0 = (const float*)d_in[4];
    const float* b0 = (const float*)d_in[5];
    const float* skip0 = (const float*)d_in[6];
    const float* g0 = (const float*)d_in[7];
    const float* be0 = (const float*)d_in[8];
    const float* W1 = (const float*)d_in[9];
    const float* as1 = (const float*)d_in[10];
    const float* ad1 = (const float*)d_in[11];
    const float* b1 = (const float*)d_in[12];
    const float* g1 = (const float*)d_in[13];
    const float* be1 = (const float*)d_in[14];
    const float* W2 = (const float*)d_in[15];
    const float* as2 = (const float*)d_in[16];
    const float* ad2 = (const float*)d_in[17];
    const float* b2 = (const float*)d_in[18];
    const float* g2 = (const float*)d_in[19];
    const float* be2 = (const float*)d_in[20];
    const float* projW = (const float*)d_in[21];
    const float* projb = (const float*)d_in[22];
    float* out = (float*)d_out;

    char* p = (char*)d_ws;
    auto alloc = [&](size_t bytes) {
        char* r = p;
        p += (bytes + 255) & ~(size_t)255;
        return r;
    };
    int* deg = (int*)alloc((size_t)NN * 4);  // reused as scatter cursor
    int* offsets = (int*)alloc((size_t)(NN + 1) * 4);
    int* partial = (int*)alloc((size_t)NB_SCAN * 4);
    int* csr_src = (int*)alloc((size_t)NE * 4);
    float* h_feat = (float*)alloc((size_t)NN * 128 * 4);
    float* e_src = (float*)alloc((size_t)NN * 2 * 4);
    float* e_dst = (float*)alloc((size_t)NN * 2 * 4);
    float* skipx = (float*)alloc((size_t)NN * 64 * 4);
    float* jk = (float*)alloc((size_t)NN * 64 * 4);
    float* xcur = (float*)alloc((size_t)NN * 64 * 4);
    float* hraw = (float*)alloc((size_t)NN * 64 * 4);
    float* bnsum = (float*)alloc(128 * 4);
    float* bnsc = (float*)alloc(128 * 4);
    if ((size_t)(p - (char*)d_ws) > ws_size) return;  // ws too small: fail loudly

    // ---- CSR build (recomputed every call; ws is re-poisoned) ----
    zero_u32<<<(NN + 255) / 256, 256, 0, stream>>>((unsigned int*)deg, NN);
    count_deg<<<(NE + 255) / 256, 256, 0, stream>>>(e_dst_idx, deg);
    scan_partial<<<NB_SCAN, 256, 0, stream>>>(deg, partial);
    scan_serial<<<1, 64, 0, stream>>>(partial, offsets);
    scan_final<<<NB_SCAN, 256, 0, stream>>>(deg, partial, offsets, deg);
    scatter_edges<<<(NE + 255) / 256, 256, 0, stream>>>(e_src_idx, e_dst_idx, deg, csr_src);

    // ---- Layer 0 ----
    gemm_kernel<128, 128><<<(NN + 15) / 16, 256, 0, stream>>>(x, W0, nullptr, h_feat);
    gemm_kernel<128, 64><<<(NN + 31) / 32, 256, 0, stream>>>(x, skip0, nullptr, skipx);
    gemm_kernel<128, 64><<<(NN + 31) / 32, 256, 0, stream>>>(x, projW, projb, jk);
    att_scores<<<(NN + 3) / 4, 256, 0, stream>>>(h_feat, as0, ad0, e_src, e_dst);
    aggregate<<<(NN + 3) / 4, 256, 0, stream>>>(offsets, csr_src, e_src, e_dst, h_feat,
                                                skipx, b0, hraw);
    zero_u32<<<1, 128, 0, stream>>>((unsigned int*)bnsum, 128);
    bn_stats<<<(NN + 511) / 512, 256, 0, stream>>>(hraw, bnsum);
    bn_final<<<1, 64, 0, stream>>>(bnsum, g0, be0, bnsc);
    bn_norm_jk<<<(NN * 64 + 255) / 256, 256, 0, stream>>>(hraw, bnsc, xcur, jk, nullptr);

    // ---- Layer 1 ----
    gemm_kernel<64, 128><<<(NN + 15) / 16, 256, 0, stream>>>(xcur, W1, nullptr, h_feat);
    att_scores<<<(NN + 3) / 4, 256, 0, stream>>>(h_feat, as1, ad1, e_src, e_dst);
    aggregate<<<(NN + 3) / 4, 256, 0, stream>>>(offsets, csr_src, e_src, e_dst, h_feat,
                                                xcur, b1, hraw);
    zero_u32<<<1, 128, 0, stream>>>((unsigned int*)bnsum, 128);
    bn_stats<<<(NN + 511) / 512, 256, 0, stream>>>(hraw, bnsum);
    bn_final<<<1, 64, 0, stream>>>(bnsum, g1, be1, bnsc);
    bn_norm_jk<<<(NN * 64 + 255) / 256, 256, 0, stream>>>(hraw, bnsc, xcur, jk, nullptr);

    // ---- Layer 2 ----
    gemm_kernel<64, 128><<<(NN + 15) / 16, 256, 0, stream>>>(xcur, W2, nullptr, h_feat);
    att_scores<<<(NN + 3) / 4, 256, 0, stream>>>(h_feat, as2, ad2, e_src, e_dst);
    aggregate<<<(NN + 3) / 4, 256, 0, stream>>>(offsets, csr_src, e_src, e_dst, h_feat,
                                                xcur, b2, hraw);
    zero_u32<<<1, 128, 0, stream>>>((unsigned int*)bnsum, 128);
    bn_stats<<<(NN + 511) / 512, 256, 0, stream>>>(hraw, bnsum);
    bn_final<<<1, 64, 0, stream>>>(bnsum, g2, be2, bnsc);
    bn_norm_jk<<<(NN * 64 + 255) / 256, 256, 0, stream>>>(hraw, bnsc, xcur, jk, out);
}

// Round 2
// 1290.974 us; speedup vs baseline: 1.1628x; 1.1628x over previous
//
#include <hip/hip_runtime.h>

#define NN 100000
#define NE 1600000

constexpr int SCAN_CHUNK = 2048;
constexpr int NB_SCAN = (NN + SCAN_CHUNK - 1) / SCAN_CHUNK;  // 49

__global__ void zero_u32(unsigned int* p, int n) {
    int i = blockIdx.x * blockDim.x + threadIdx.x;
    if (i < n) p[i] = 0u;
}

__global__ void count_deg(const int* __restrict__ dst, int* __restrict__ deg) {
    int i = blockIdx.x * blockDim.x + threadIdx.x;
    if (i < NE) atomicAdd(&deg[dst[i]], 1);
}

__global__ void scan_partial(const int* __restrict__ deg, int* __restrict__ partial) {
    __shared__ int ls[256];
    int base = blockIdx.x * SCAN_CHUNK;
    int t = threadIdx.x;
    int s = 0;
    for (int j = 0; j < SCAN_CHUNK; j += 256) {
        int i = base + j + t;
        if (i < NN) s += deg[i];
    }
    ls[t] = s;
    __syncthreads();
    for (int off = 128; off > 0; off >>= 1) {
        if (t < off) ls[t] += ls[t + off];
        __syncthreads();
    }
    if (t == 0) partial[blockIdx.x] = ls[0];
}

__global__ void scan_serial(int* partial, int* offsets) {
    if (threadIdx.x == 0) {
        int run = 0;
        for (int b = 0; b < NB_SCAN; ++b) {
            int v = partial[b];
            partial[b] = run;
            run += v;
        }
        offsets[NN] = NE;
    }
}

__global__ void scan_final(const int* __restrict__ deg, const int* __restrict__ partial,
                           int* __restrict__ offsets, int* __restrict__ cursor) {
    __shared__ int tot[256];
    int t = threadIdx.x;
    int base = blockIdx.x * SCAN_CHUNK + t * 8;
    int d[8];
    int s = 0;
#pragma unroll
    for (int j = 0; j < 8; ++j) {
        int i = base + j;
        d[j] = (i < NN) ? deg[i] : 0;
        s += d[j];
    }
    tot[t] = s;
    __syncthreads();
    int pre = partial[blockIdx.x];
    for (int j = 0; j < t; ++j) pre += tot[j];
#pragma unroll
    for (int j = 0; j < 8; ++j) {
        int i = base + j;
        if (i < NN) {
            offsets[i] = pre;
            cursor[i] = pre;
        }
        pre += d[j];
    }
}

__global__ void scatter_edges(const int* __restrict__ src, const int* __restrict__ dst,
                              int* __restrict__ cursor, int* __restrict__ csr_src) {
    int i = blockIdx.x * blockDim.x + threadIdx.x;
    if (i < NE) {
        int pos = atomicAdd(&cursor[dst[i]], 1);
        csr_src[pos] = src[i];
    }
}

// Y[N,KOUT] = X[N,KIN] @ W[KIN,KOUT] (+bias). 256 threads, each 4 rows x 4
// cols in registers; X staged transposed (K-major) in LDS so the row fragment
// is one broadcast ds_read_b128; W chunk staged row-major, float4 reads.
// TOUT: write in [N][64][2] head-interleaved layout (for the gather kernel).
// XFORM (KIN==64 only): X element = lrelu(bn(hraw)) computed on the fly, and
// jk[idx] = max(jk[idx], v) updated (each element staged by exactly one block).
template <int KIN, int KOUT, bool TOUT, bool XFORM>
__global__ __launch_bounds__(256) void gemm_kernel(
    const float* __restrict__ X, const float* __restrict__ W,
    const float* __restrict__ bias, float* __restrict__ Y,
    const float* __restrict__ bnsc, float* __restrict__ jk) {
    constexpr int CG = KOUT / 4;        // col groups
    constexpr int ROWS = 4096 / KOUT;   // rows per block (32 or 64)
    constexpr int RP = ROWS + 4;        // pad: bank spread + keeps 16B align
    constexpr int KCHUNK = (KIN < 64) ? KIN : 64;
    __shared__ float XsT[KIN * RP];
    __shared__ float Ws[KCHUNK * KOUT];
    int t = threadIdx.x;
    int rbase = blockIdx.x * ROWS;
    for (int i = t; i < ROWS * KIN; i += 256) {
        int r = i / KIN, k = i % KIN;
        int gr = rbase + r;
        float v = 0.f;
        if (gr < NN) {
            v = X[gr * KIN + k];
            if (XFORM) {
                v = v * bnsc[k] + bnsc[64 + k];
                v = v >= 0.f ? v : 0.01f * v;
                int idx = gr * 64 + k;
                jk[idx] = fmaxf(jk[idx], v);
            }
        }
        XsT[k * RP + r] = v;
    }
    int tc = t % CG, tr = t / CG;
    float acc[4][4];
#pragma unroll
    for (int i = 0; i < 4; ++i)
#pragma unroll
        for (int j = 0; j < 4; ++j) acc[i][j] = 0.f;
    for (int kc = 0; kc < KIN; kc += KCHUNK) {
        __syncthreads();
        for (int i = t; i < KCHUNK * KOUT; i += 256)
            Ws[i] = W[(kc + i / KOUT) * KOUT + i % KOUT];
        __syncthreads();
#pragma unroll 4
        for (int k = 0; k < KCHUNK; ++k) {
            float4 wv = *(const float4*)&Ws[k * KOUT + tc * 4];
            float4 xv = *(const float4*)&XsT[(kc + k) * RP + tr * 4];
            acc[0][0] += xv.x * wv.x; acc[0][1] += xv.x * wv.y;
            acc[0][2] += xv.x * wv.z; acc[0][3] += xv.x * wv.w;
            acc[1][0] += xv.y * wv.x; acc[1][1] += xv.y * wv.y;
            acc[1][2] += xv.y * wv.z; acc[1][3] += xv.y * wv.w;
            acc[2][0] += xv.z * wv.x; acc[2][1] += xv.z * wv.y;
            acc[2][2] += xv.z * wv.z; acc[2][3] += xv.z * wv.w;
            acc[3][0] += xv.w * wv.x; acc[3][1] += xv.w * wv.y;
            acc[3][2] += xv.w * wv.z; acc[3][3] += xv.w * wv.w;
        }
    }
#pragma unroll
    for (int i = 0; i < 4; ++i) {
        int gr = rbase + tr * 4 + i;
        if (gr < NN) {
#pragma unroll
            for (int j = 0; j < 4; ++j) {
                int cg = tc * 4 + j;
                float v = acc[i][j] + (bias ? bias[cg] : 0.f);
                if (TOUT)
                    Y[gr * 128 + (cg & 63) * 2 + (cg >> 6)] = v;
                else
                    Y[gr * KOUT + cg] = v;
            }
        }
    }
}

// e_src[n,h] = <h[n,h,:], a_src[h,:]>, e_dst likewise. One wave per node,
// lane = channel; h is in [N][64][2] head-interleaved layout.
__global__ void att_scores(const float* __restrict__ h, const float* __restrict__ as,
                           const float* __restrict__ ad, float* __restrict__ e_src,
                           float* __restrict__ e_dst) {
    int wave = threadIdx.x >> 6;
    int lane = threadIdx.x & 63;
    int n = blockIdx.x * 4 + wave;
    if (n >= NN) return;
    float2 v = *(const float2*)&h[n * 128 + lane * 2];
    float s0 = v.x * as[lane], s1 = v.y * as[64 + lane];
    float d0 = v.x * ad[lane], d1 = v.y * ad[64 + lane];
    for (int off = 32; off > 0; off >>= 1) {
        s0 += __shfl_xor(s0, off, 64);
        s1 += __shfl_xor(s1, off, 64);
        d0 += __shfl_xor(d0, off, 64);
        d1 += __shfl_xor(d1, off, 64);
    }
    if (lane == 0) {
        e_src[n * 2] = s0;
        e_src[n * 2 + 1] = s1;
        e_dst[n * 2] = d0;
        e_dst[n * 2 + 1] = d1;
    }
}

// One wave per destination node, single pass (no max subtraction: |e| is O(3),
// exp is safe, softmax ratio is identical). lane = channel, float2 = 2 heads.
// 2x manual unroll so two edges' gather chains overlap.
__global__ __launch_bounds__(256) void aggregate(
    const int* __restrict__ offsets, const int* __restrict__ csr_src,
    const float* __restrict__ e_src, const float* __restrict__ e_dst,
    const float* __restrict__ h, const float* __restrict__ skipsrc,
    const float* __restrict__ bnsc, const float* __restrict__ bias,
    float* __restrict__ hraw) {
    int wave = threadIdx.x >> 6;
    int lane = threadIdx.x & 63;
    int n = blockIdx.x * 4 + wave;
    if (n >= NN) return;
    int beg = offsets[n], end = offsets[n + 1];
    float2 ed = *(const float2*)&e_dst[n * 2];
    float acc0 = 0.f, acc1 = 0.f, den0 = 0.f, den1 = 0.f;
    int j = beg;
    for (; j + 1 < end; j += 2) {
        int s0 = csr_src[j];
        int s1 = csr_src[j + 1];
        float2 es0 = *(const float2*)&e_src[s0 * 2];
        float2 es1 = *(const float2*)&e_src[s1 * 2];
        float2 h0 = *(const float2*)&h[s0 * 128 + lane * 2];
        float2 h1 = *(const float2*)&h[s1 * 128 + lane * 2];
        float a00 = es0.x + ed.x, a01 = es0.y + ed.y;
        float a10 = es1.x + ed.x, a11 = es1.y + ed.y;
        a00 = a00 >= 0.f ? a00 : 0.2f * a00;
        a01 = a01 >= 0.f ? a01 : 0.2f * a01;
        a10 = a10 >= 0.f ? a10 : 0.2f * a10;
        a11 = a11 >= 0.f ? a11 : 0.2f * a11;
        float w00 = __expf(a00), w01 = __expf(a01);
        float w10 = __expf(a10), w11 = __expf(a11);
        den0 += w00 + w10;
        den1 += w01 + w11;
        acc0 += w00 * h0.x + w10 * h1.x;
        acc1 += w01 * h0.y + w11 * h1.y;
    }
    if (j < end) {
        int s0 = csr_src[j];
        float2 es0 = *(const float2*)&e_src[s0 * 2];
        float2 h0 = *(const float2*)&h[s0 * 128 + lane * 2];
        float a00 = es0.x + ed.x, a01 = es0.y + ed.y;
        a00 = a00 >= 0.f ? a00 : 0.2f * a00;
        a01 = a01 >= 0.f ? a01 : 0.2f * a01;
        float w00 = __expf(a00), w01 = __expf(a01);
        den0 += w00;
        den1 += w01;
        acc0 += w00 * h0.x;
        acc1 += w01 * h0.y;
    }
    float sv = skipsrc[n * 64 + lane];
    if (bnsc) {  // identity skip from previous layer's pre-BN buffer
        sv = sv * bnsc[lane] + bnsc[64 + lane];
        sv = sv >= 0.f ? sv : 0.01f * sv;
    }
    float o = 0.5f * (acc0 / (den0 + 1e-16f) + acc1 / (den1 + 1e-16f)) + bias[lane] + sv;
    hraw[n * 64 + lane] = o;
}

__global__ void bn_stats(const float* __restrict__ x, float* __restrict__ sums) {
    __shared__ float ls[256], ls2[256];
    int t = threadIdx.x;
    int c = t & 63, q = t >> 6;
    float s = 0.f, s2 = 0.f;
    int rbeg = blockIdx.x * 512;
    for (int r = rbeg + q; r < rbeg + 512; r += 4) {
        if (r < NN) {
            float v = x[r * 64 + c];
            s += v;
            s2 += v * v;
        }
    }
    ls[t] = s;
    ls2[t] = s2;
    __syncthreads();
    if (t < 64) {
        s = ls[t] + ls[t + 64] + ls[t + 128] + ls[t + 192];
        s2 = ls2[t] + ls2[t + 64] + ls2[t + 128] + ls2[t + 192];
        atomicAdd(&sums[c], s);
        atomicAdd(&sums[64 + c], s2);
    }
}

__global__ void bn_final(const float* __restrict__ sums, const float* __restrict__ g,
                         const float* __restrict__ be, float* __restrict__ sc_sh) {
    int c = threadIdx.x;
    if (c < 64) {
        float mu = sums[c] / (float)NN;
        float var = sums[64 + c] / (float)NN - mu * mu;
        float sc = g[c] * rsqrtf(var + 1e-5f);
        sc_sh[c] = sc;
        sc_sh[64 + c] = be[c] - mu * sc;
    }
}

__global__ void final_out(const float* __restrict__ hraw, const float* __restrict__ sc_sh,
                          const float* __restrict__ jk, float* __restrict__ out) {
    int i = blockIdx.x * blockDim.x + threadIdx.x;
    if (i < NN * 64) {
        int c = i & 63;
        float v = hraw[i] * sc_sh[c] + sc_sh[64 + c];
        v = v >= 0.f ? v : 0.01f * v;
        out[i] = fmaxf(jk[i], v);
    }
}

extern "C" void kernel_launch(void* const* d_in, const int* in_sizes, int n_in,
                              void* d_out, int out_size, void* d_ws, size_t ws_size,
                              hipStream_t stream) {
    const float* x = (const float*)d_in[0];
    const int* ei = (const int*)d_in[1];
    const int* e_src_idx = ei;
    const int* e_dst_idx = ei + NE;
    const float* W0 = (const float*)d_in[2];
    const float* as0 = (const float*)d_in[3];
    const float* ad0 = (const float*)d_in[4];
    const float* b0 = (const float*)d_in[5];
    const float* skip0 = (const float*)d_in[6];
    const float* g0 = (const float*)d_in[7];
    const float* be0 = (const float*)d_in[8];
    const float* W1 = (const float*)d_in[9];
    const float* as1 = (const float*)d_in[10];
    const float* ad1 = (const float*)d_in[11];
    const float* b1 = (const float*)d_in[12];
    const float* g1 = (const float*)d_in[13];
    const float* be1 = (const float*)d_in[14];
    const float* W2 = (const float*)d_in[15];
    const float* as2 = (const float*)d_in[16];
    const float* ad2 = (const float*)d_in[17];
    const float* b2 = (const float*)d_in[18];
    const float* g2 = (const float*)d_in[19];
    const float* be2 = (const float*)d_in[20];
    const float* projW = (const float*)d_in[21];
    const float* projb = (const float*)d_in[22];
    float* out = (float*)d_out;

    char* p = (char*)d_ws;
    auto alloc = [&](size_t bytes) {
        char* r = p;
        p += (bytes + 255) & ~(size_t)255;
        return r;
    };
    int* deg = (int*)alloc((size_t)NN * 4);  // reused as scatter cursor
    int* offsets = (int*)alloc((size_t)(NN + 1) * 4);
    int* partial = (int*)alloc((size_t)NB_SCAN * 4);
    int* csr_src = (int*)alloc((size_t)NE * 4);
    float* h_feat = (float*)alloc((size_t)NN * 128 * 4);
    float* e_src = (float*)alloc((size_t)NN * 2 * 4);
    float* e_dst = (float*)alloc((size_t)NN * 2 * 4);
    float* skipx = (float*)alloc((size_t)NN * 64 * 4);
    float* jk = (float*)alloc((size_t)NN * 64 * 4);
    float* hrawA = (float*)alloc((size_t)NN * 64 * 4);
    float* hrawB = (float*)alloc((size_t)NN * 64 * 4);
    float* bnsum = (float*)alloc(128 * 4);
    float* bnsc = (float*)alloc(128 * 4);
    if ((size_t)(p - (char*)d_ws) > ws_size) return;

    // ---- CSR by destination ----
    zero_u32<<<(NN + 255) / 256, 256, 0, stream>>>((unsigned int*)deg, NN);
    count_deg<<<(NE + 255) / 256, 256, 0, stream>>>(e_dst_idx, deg);
    scan_partial<<<NB_SCAN, 256, 0, stream>>>(deg, partial);
    scan_serial<<<1, 64, 0, stream>>>(partial, offsets);
    scan_final<<<NB_SCAN, 256, 0, stream>>>(deg, partial, offsets, deg);
    scatter_edges<<<(NE + 255) / 256, 256, 0, stream>>>(e_src_idx, e_dst_idx, deg, csr_src);

    // ---- Layer 0 ----
    gemm_kernel<128, 128, true, false><<<(NN + 31) / 32, 256, 0, stream>>>(
        x, W0, nullptr, h_feat, nullptr, nullptr);
    gemm_kernel<128, 64, false, false><<<(NN + 63) / 64, 256, 0, stream>>>(
        x, skip0, nullptr, skipx, nullptr, nullptr);
    gemm_kernel<128, 64, false, false><<<(NN + 63) / 64, 256, 0, stream>>>(
        x, projW, projb, jk, nullptr, nullptr);
    att_scores<<<(NN + 3) / 4, 256, 0, stream>>>(h_feat, as0, ad0, e_src, e_dst);
    aggregate<<<(NN + 3) / 4, 256, 0, stream>>>(offsets, csr_src, e_src, e_dst, h_feat,
                                                skipx, nullptr, b0, hrawA);
    zero_u32<<<1, 128, 0, stream>>>((unsigned int*)bnsum, 128);
    bn_stats<<<(NN + 511) / 512, 256, 0, stream>>>(hrawA, bnsum);
    bn_final<<<1, 64, 0, stream>>>(bnsum, g0, be0, bnsc);

    // ---- Layer 1 (X = lrelu(bn0(hrawA)) built in GEMM staging; jk updated) ----
    gemm_kernel<64, 128, true, true><<<(NN + 31) / 32, 256, 0, stream>>>(
        hrawA, W1, nullptr, h_feat, bnsc, jk);
    att_scores<<<(NN + 3) / 4, 256, 0, stream>>>(h_feat, as1, ad1, e_src, e_dst);
    aggregate<<<(NN + 3) / 4, 256, 0, stream>>>(offsets, csr_src, e_src, e_dst, h_feat,
                                                hrawA, bnsc, b1, hrawB);
    zero_u32<<<1, 128, 0, stream>>>((unsigned int*)bnsum, 128);
    bn_stats<<<(NN + 511) / 512, 256, 0, stream>>>(hrawB, bnsum);
    bn_final<<<1, 64, 0, stream>>>(bnsum, g1, be1, bnsc);

    // ---- Layer 2 ----
    gemm_kernel<64, 128, true, true><<<(NN + 31) / 32, 256, 0, stream>>>(
        hrawB, W2, nullptr, h_feat, bnsc, jk);
    att_scores<<<(NN + 3) / 4, 256, 0, stream>>>(h_feat, as2, ad2, e_src, e_dst);
    aggregate<<<(NN + 3) / 4, 256, 0, stream>>>(offsets, csr_src, e_src, e_dst, h_feat,
                                                hrawB, bnsc, b2, hrawA);
    zero_u32<<<1, 128, 0, stream>>>((unsigned int*)bnsum, 128);
    bn_stats<<<(NN + 511) / 512, 256, 0, stream>>>(hrawA, bnsum);
    bn_final<<<1, 64, 0, stream>>>(bnsum, g2, be2, bnsc);

    final_out<<<(NN * 64 + 255) / 256, 256, 0, stream>>>(hrawA, bnsc, jk, out);
}

// Round 3
// 968.995 us; speedup vs baseline: 1.5491x; 1.3323x over previous
//
#include <hip/hip_runtime.h>

#define NN 100000
#define NE 1600000

constexpr int SCAN_CHUNK = 2048;
constexpr int NB_SCAN = (NN + SCAN_CHUNK - 1) / SCAN_CHUNK;  // 49

typedef __attribute__((ext_vector_type(8))) short s16x8;
typedef __attribute__((ext_vector_type(4))) float f32x4;

__device__ inline unsigned short f2bf(float f) {  // RNE fp32 -> bf16 bits
    unsigned int u = __float_as_uint(f);
    return (unsigned short)((u + 0x7fffu + ((u >> 16) & 1u)) >> 16);
}
__device__ inline float bf_lo(unsigned int pk) { return __uint_as_float(pk << 16); }
__device__ inline float bf_hi(unsigned int pk) { return __uint_as_float(pk & 0xffff0000u); }

__global__ void zero_u32(unsigned int* p, int n) {
    int i = blockIdx.x * blockDim.x + threadIdx.x;
    if (i < n) p[i] = 0u;
}

__global__ void count_deg(const int* __restrict__ dst, int* __restrict__ deg) {
    int i = blockIdx.x * blockDim.x + threadIdx.x;
    if (i < NE) atomicAdd(&deg[dst[i]], 1);
}

__global__ void scan_partial(const int* __restrict__ deg, int* __restrict__ partial) {
    __shared__ int ls[256];
    int base = blockIdx.x * SCAN_CHUNK;
    int t = threadIdx.x;
    int s = 0;
    for (int j = 0; j < SCAN_CHUNK; j += 256) {
        int i = base + j + t;
        if (i < NN) s += deg[i];
    }
    ls[t] = s;
    __syncthreads();
    for (int off = 128; off > 0; off >>= 1) {
        if (t < off) ls[t] += ls[t + off];
        __syncthreads();
    }
    if (t == 0) partial[blockIdx.x] = ls[0];
}

__global__ void scan_serial(int* partial, int* offsets) {
    if (threadIdx.x == 0) {
        int run = 0;
        for (int b = 0; b < NB_SCAN; ++b) {
            int v = partial[b];
            partial[b] = run;
            run += v;
        }
        offsets[NN] = NE;
    }
}

__global__ void scan_final(const int* __restrict__ deg, const int* __restrict__ partial,
                           int* __restrict__ offsets, int* __restrict__ cursor) {
    __shared__ int tot[256];
    int t = threadIdx.x;
    int base = blockIdx.x * SCAN_CHUNK + t * 8;
    int d[8];
    int s = 0;
#pragma unroll
    for (int j = 0; j < 8; ++j) {
        int i = base + j;
        d[j] = (i < NN) ? deg[i] : 0;
        s += d[j];
    }
    tot[t] = s;
    __syncthreads();
    int pre = partial[blockIdx.x];
    for (int j = 0; j < t; ++j) pre += tot[j];
#pragma unroll
    for (int j = 0; j < 8; ++j) {
        int i = base + j;
        if (i < NN) {
            offsets[i] = pre;
            cursor[i] = pre;
        }
        pre += d[j];
    }
}

__global__ void scatter_edges(const int* __restrict__ src, const int* __restrict__ dst,
                              int* __restrict__ cursor, int* __restrict__ csr_src,
                              int* __restrict__ csr_dst) {
    int i = blockIdx.x * blockDim.x + threadIdx.x;
    if (i < NE) {
        int d = dst[i];
        int pos = atomicAdd(&cursor[d], 1);
        csr_src[pos] = src[i];
        csr_dst[pos] = d;
    }
}

// Transpose + fp32->bf16 all weights once per launch.
// Wtcat[256][128]: cols(oc) 0..127 = W0, 128..191 = skip0, 192..255 = projW.
// Wt1/Wt2: [128][64].
__global__ void prep_weights(const float* __restrict__ W0, const float* __restrict__ skip0,
                             const float* __restrict__ projW, const float* __restrict__ W1,
                             const float* __restrict__ W2, unsigned short* __restrict__ Wtcat,
                             unsigned short* __restrict__ Wt1, unsigned short* __restrict__ Wt2) {
    int i = blockIdx.x * 256 + threadIdx.x;
    if (i < 32768) {
        int oc = i >> 7, k = i & 127;
        float v;
        if (oc < 128) v = W0[k * 128 + oc];
        else if (oc < 192) v = skip0[k * 64 + (oc - 128)];
        else v = projW[k * 64 + (oc - 192)];
        Wtcat[oc * 128 + k] = f2bf(v);
    } else if (i < 40960) {
        int j = i - 32768, oc = j >> 6, k = j & 63;
        Wt1[oc * 64 + k] = f2bf(W1[k * 128 + oc]);
    } else if (i < 49152) {
        int j = i - 40960, oc = j >> 6, k = j & 63;
        Wt2[oc * 64 + k] = f2bf(W2[k * 128 + oc]);
    }
}

// MFMA bf16 GEMM: block = 64 rows x 128 cols, 4 waves (wave = 16 rows).
// X fp32 [N][K] staged to LDS bf16 (optionally BN+lrelu transformed, with JK
// max update); Wt bf16 [col][K] staged to LDS. 16x16x32 mfma, fp32 acc.
// L0: blockIdx.y==0 -> packed-bf16 h out; y==1 -> skip (fp32) + proj (+bias).
// !L0: packed h out only.
template <int K, bool L0, bool XFORM>
__global__ __launch_bounds__(256) void gemm_mfma(
    const float* __restrict__ X, const unsigned short* __restrict__ Wt,
    unsigned int* __restrict__ Hpk, float* __restrict__ skipx, float* __restrict__ jkproj,
    const float* __restrict__ projb, const float* __restrict__ bnsc,
    float* __restrict__ jkmax) {
    constexpr int KP = K + 8;
    __shared__ unsigned short As[64 * KP];
    __shared__ unsigned short Bs[128 * KP];
    int t = threadIdx.x;
    int rbase = blockIdx.x * 64;
    const unsigned short* Wtg = Wt + (size_t)blockIdx.y * 128 * K;

    // Stage A (64 x K fp32 -> bf16), float4 granularity.
    for (int i = t; i < 64 * (K / 4); i += 256) {
        int r = i / (K / 4);
        int kq = (i % (K / 4)) * 4;
        int gr = rbase + r;
        float4 v = make_float4(0.f, 0.f, 0.f, 0.f);
        if (gr < NN) {
            v = *(const float4*)&X[(size_t)gr * K + kq];
            if (XFORM) {
                float* vc = (float*)&v;
#pragma unroll
                for (int c = 0; c < 4; ++c) {
                    float val = vc[c] * bnsc[kq + c] + bnsc[64 + kq + c];
                    val = val >= 0.f ? val : 0.01f * val;
                    int idx = gr * 64 + kq + c;
                    jkmax[idx] = fmaxf(jkmax[idx], val);
                    vc[c] = val;
                }
            }
        }
        uint2 u;
        u.x = (unsigned int)f2bf(v.x) | ((unsigned int)f2bf(v.y) << 16);
        u.y = (unsigned int)f2bf(v.z) | ((unsigned int)f2bf(v.w) << 16);
        *(uint2*)&As[r * KP + kq] = u;
    }
    // Stage B (128 cols x K bf16), uint4 granularity.
    for (int i = t; i < 128 * (K / 8); i += 256) {
        int oc = i / (K / 8);
        int k8 = (i % (K / 8)) * 8;
        uint4 v = *(const uint4*)&Wtg[(size_t)oc * K + k8];
        *(uint4*)&Bs[oc * KP + k8] = v;
    }
    __syncthreads();

    int lane = t & 63, wv = t >> 6;
    int lr = lane & 15, quad = lane >> 4;
    int arow = wv * 16 + lr;
    f32x4 acc[8];
#pragma unroll
    for (int c = 0; c < 8; ++c) acc[c] = (f32x4)(0.f);
#pragma unroll
    for (int k0 = 0; k0 < K; k0 += 32) {
        s16x8 a = *(const s16x8*)&As[arow * KP + k0 + quad * 8];
#pragma unroll
        for (int ct = 0; ct < 8; ++ct) {
            s16x8 b = *(const s16x8*)&Bs[(ct * 16 + lr) * KP + k0 + quad * 8];
            acc[ct] = __builtin_amdgcn_mfma_f32_16x16x32_bf16(a, b, acc[ct], 0, 0, 0);
        }
    }

    bool packed = (!L0) || (blockIdx.y == 0);
#pragma unroll
    for (int reg = 0; reg < 4; ++reg) {
        int row = rbase + wv * 16 + quad * 4 + reg;
        if (row >= NN) continue;
        if (packed) {
#pragma unroll
            for (int ct = 0; ct < 4; ++ct) {
                unsigned int pk = (unsigned int)f2bf(acc[ct][reg]) |
                                  ((unsigned int)f2bf(acc[ct + 4][reg]) << 16);
                Hpk[(size_t)row * 64 + ct * 16 + lr] = pk;
            }
        } else {
#pragma unroll
            for (int ct = 0; ct < 4; ++ct)
                skipx[(size_t)row * 64 + ct * 16 + lr] = acc[ct][reg];
#pragma unroll
            for (int ct = 4; ct < 8; ++ct) {
                int c = (ct - 4) * 16 + lr;
                jkproj[(size_t)row * 64 + c] = acc[ct][reg] + projb[c];
            }
        }
    }
}

// e_src[n,h] = <h[n,h,:], a_src[h,:]> on packed-bf16 h. One wave per node.
__global__ void att_scores(const unsigned int* __restrict__ Hpk, const float* __restrict__ as,
                           const float* __restrict__ ad, float* __restrict__ e_src,
                           float* __restrict__ e_dst) {
    int wave = threadIdx.x >> 6;
    int lane = threadIdx.x & 63;
    int n = blockIdx.x * 4 + wave;
    if (n >= NN) return;
    unsigned int pk = Hpk[(size_t)n * 64 + lane];
    float h0 = bf_lo(pk), h1 = bf_hi(pk);
    float s0 = h0 * as[lane], s1 = h1 * as[64 + lane];
    float d0 = h0 * ad[lane], d1 = h1 * ad[64 + lane];
    for (int off = 32; off > 0; off >>= 1) {
        s0 += __shfl_xor(s0, off, 64);
        s1 += __shfl_xor(s1, off, 64);
        d0 += __shfl_xor(d0, off, 64);
        d1 += __shfl_xor(d1, off, 64);
    }
    if (lane == 0) {
        e_src[n * 2] = s0;
        e_src[n * 2 + 1] = s1;
        e_dst[n * 2] = d0;
        e_dst[n * 2 + 1] = d1;
    }
}

// Per-edge unnormalized softmax weights, CSR order (coalesced in j).
__global__ void edge_w(const int* __restrict__ csr_src, const int* __restrict__ csr_dst,
                       const float* __restrict__ e_src, const float* __restrict__ e_dst,
                       float2* __restrict__ walpha) {
    int i = blockIdx.x * blockDim.x + threadIdx.x;
    if (i >= NE) return;
    int s = csr_src[i], d = csr_dst[i];
    float2 es = *(const float2*)&e_src[s * 2];
    float2 ed = *(const float2*)&e_dst[d * 2];
    float a0 = es.x + ed.x, a1 = es.y + ed.y;
    a0 = a0 >= 0.f ? a0 : 0.2f * a0;
    a1 = a1 >= 0.f ? a1 : 0.2f * a1;
    walpha[i] = make_float2(__expf(a0), __expf(a1));
}

// One wave per destination node. Inner loop: uniform csr/weight loads + one
// 4B packed-bf16 gather per lane per edge + 4 FMA. No exp/leaky in-loop.
__global__ __launch_bounds__(256) void aggregate(
    const int* __restrict__ offsets, const int* __restrict__ csr_src,
    const float2* __restrict__ walpha, const unsigned int* __restrict__ Hpk,
    const float* __restrict__ skipsrc, const float* __restrict__ bnsc,
    const float* __restrict__ bias, float* __restrict__ hraw) {
    int wave = threadIdx.x >> 6;
    int lane = threadIdx.x & 63;
    int n = blockIdx.x * 4 + wave;
    if (n >= NN) return;
    int beg = offsets[n], end = offsets[n + 1];
    float acc0 = 0.f, acc1 = 0.f, den0 = 0.f, den1 = 0.f;
    int j = beg;
    for (; j + 1 < end; j += 2) {
        int s0 = csr_src[j];
        int s1 = csr_src[j + 1];
        float2 w0 = walpha[j];
        float2 w1 = walpha[j + 1];
        unsigned int p0 = Hpk[(size_t)s0 * 64 + lane];
        unsigned int p1 = Hpk[(size_t)s1 * 64 + lane];
        den0 += w0.x + w1.x;
        den1 += w0.y + w1.y;
        acc0 += w0.x * bf_lo(p0) + w1.x * bf_lo(p1);
        acc1 += w0.y * bf_hi(p0) + w1.y * bf_hi(p1);
    }
    if (j < end) {
        int s0 = csr_src[j];
        float2 w0 = walpha[j];
        unsigned int p0 = Hpk[(size_t)s0 * 64 + lane];
        den0 += w0.x;
        den1 += w0.y;
        acc0 += w0.x * bf_lo(p0);
        acc1 += w0.y * bf_hi(p0);
    }
    float sv = skipsrc[(size_t)n * 64 + lane];
    if (bnsc) {  // identity skip from previous layer's pre-BN buffer
        sv = sv * bnsc[lane] + bnsc[64 + lane];
        sv = sv >= 0.f ? sv : 0.01f * sv;
    }
    float o = 0.5f * (acc0 / (den0 + 1e-16f) + acc1 / (den1 + 1e-16f)) + bias[lane] + sv;
    hraw[(size_t)n * 64 + lane] = o;
}

__global__ void bn_stats(const float* __restrict__ x, float* __restrict__ sums) {
    __shared__ float ls[256], ls2[256];
    int t = threadIdx.x;
    int c = t & 63, q = t >> 6;
    float s = 0.f, s2 = 0.f;
    int rbeg = blockIdx.x * 512;
    for (int r = rbeg + q; r < rbeg + 512; r += 4) {
        if (r < NN) {
            float v = x[(size_t)r * 64 + c];
            s += v;
            s2 += v * v;
        }
    }
    ls[t] = s;
    ls2[t] = s2;
    __syncthreads();
    if (t < 64) {
        s = ls[t] + ls[t + 64] + ls[t + 128] + ls[t + 192];
        s2 = ls2[t] + ls2[t + 64] + ls2[t + 128] + ls2[t + 192];
        atomicAdd(&sums[c], s);
        atomicAdd(&sums[64 + c], s2);
    }
}

__global__ void bn_final(const float* __restrict__ sums, const float* __restrict__ g,
                         const float* __restrict__ be, float* __restrict__ sc_sh) {
    int c = threadIdx.x;
    if (c < 64) {
        float mu = sums[c] / (float)NN;
        float var = sums[64 + c] / (float)NN - mu * mu;
        float sc = g[c] * rsqrtf(var + 1e-5f);
        sc_sh[c] = sc;
        sc_sh[64 + c] = be[c] - mu * sc;
    }
}

__global__ void final_out(const float* __restrict__ hraw, const float* __restrict__ sc_sh,
                          const float* __restrict__ jk, float* __restrict__ out) {
    int i = blockIdx.x * blockDim.x + threadIdx.x;
    if (i < NN * 64) {
        int c = i & 63;
        float v = hraw[i] * sc_sh[c] + sc_sh[64 + c];
        v = v >= 0.f ? v : 0.01f * v;
        out[i] = fmaxf(jk[i], v);
    }
}

extern "C" void kernel_launch(void* const* d_in, const int* in_sizes, int n_in,
                              void* d_out, int out_size, void* d_ws, size_t ws_size,
                              hipStream_t stream) {
    const float* x = (const float*)d_in[0];
    const int* ei = (const int*)d_in[1];
    const int* e_src_idx = ei;
    const int* e_dst_idx = ei + NE;
    const float* W0 = (const float*)d_in[2];
    const float* as0 = (const float*)d_in[3];
    const float* ad0 = (const float*)d_in[4];
    const float* b0 = (const float*)d_in[5];
    const float* skip0 = (const float*)d_in[6];
    const float* g0 = (const float*)d_in[7];
    const float* be0 = (const float*)d_in[8];
    const float* W1 = (const float*)d_in[9];
    const float* as1 = (const float*)d_in[10];
    const float* ad1 = (const float*)d_in[11];
    const float* b1 = (const float*)d_in[12];
    const float* g1 = (const float*)d_in[13];
    const float* be1 = (const float*)d_in[14];
    const float* W2 = (const float*)d_in[15];
    const float* as2 = (const float*)d_in[16];
    const float* ad2 = (const float*)d_in[17];
    const float* b2 = (const float*)d_in[18];
    const float* g2 = (const float*)d_in[19];
    const float* be2 = (const float*)d_in[20];
    const float* projW = (const float*)d_in[21];
    const float* projb = (const float*)d_in[22];
    float* out = (float*)d_out;

    char* p = (char*)d_ws;
    auto alloc = [&](size_t bytes) {
        char* r = p;
        p += (bytes + 255) & ~(size_t)255;
        return r;
    };
    int* deg = (int*)alloc((size_t)NN * 4);  // reused as scatter cursor
    int* offsets = (int*)alloc((size_t)(NN + 1) * 4);
    int* partial = (int*)alloc((size_t)NB_SCAN * 4);
    int* csr_src = (int*)alloc((size_t)NE * 4);
    int* csr_dst = (int*)alloc((size_t)NE * 4);
    float2* walpha = (float2*)alloc((size_t)NE * 8);
    unsigned int* h_pk = (unsigned int*)alloc((size_t)NN * 64 * 4);
    float* e_src = (float*)alloc((size_t)NN * 2 * 4);
    float* e_dst = (float*)alloc((size_t)NN * 2 * 4);
    float* skipx = (float*)alloc((size_t)NN * 64 * 4);
    float* jk = (float*)alloc((size_t)NN * 64 * 4);
    float* hrawA = (float*)alloc((size_t)NN * 64 * 4);
    float* hrawB = (float*)alloc((size_t)NN * 64 * 4);
    unsigned short* Wtcat = (unsigned short*)alloc(256 * 128 * 2);
    unsigned short* Wt1 = (unsigned short*)alloc(128 * 64 * 2);
    unsigned short* Wt2 = (unsigned short*)alloc(128 * 64 * 2);
    float* bnsum = (float*)alloc(128 * 4);
    float* bnsc = (float*)alloc(128 * 4);
    if ((size_t)(p - (char*)d_ws) > ws_size) return;

    // ---- CSR by destination + weight prep ----
    zero_u32<<<(NN + 255) / 256, 256, 0, stream>>>((unsigned int*)deg, NN);
    count_deg<<<(NE + 255) / 256, 256, 0, stream>>>(e_dst_idx, deg);
    scan_partial<<<NB_SCAN, 256, 0, stream>>>(deg, partial);
    scan_serial<<<1, 64, 0, stream>>>(partial, offsets);
    scan_final<<<NB_SCAN, 256, 0, stream>>>(deg, partial, offsets, deg);
    scatter_edges<<<(NE + 255) / 256, 256, 0, stream>>>(e_src_idx, e_dst_idx, deg, csr_src,
                                                        csr_dst);
    prep_weights<<<192, 256, 0, stream>>>(W0, skip0, projW, W1, W2, Wtcat, Wt1, Wt2);

    int gblocks = (NN + 63) / 64;  // 1563

    // ---- Layer 0 (one GEMM: h | skip | proj) ----
    gemm_mfma<128, true, false><<<dim3(gblocks, 2), 256, 0, stream>>>(
        x, Wtcat, h_pk, skipx, jk, projb, nullptr, nullptr);
    att_scores<<<(NN + 3) / 4, 256, 0, stream>>>(h_pk, as0, ad0, e_src, e_dst);
    edge_w<<<(NE + 255) / 256, 256, 0, stream>>>(csr_src, csr_dst, e_src, e_dst, walpha);
    aggregate<<<(NN + 3) / 4, 256, 0, stream>>>(offsets, csr_src, walpha, h_pk, skipx,
                                                nullptr, b0, hrawA);
    zero_u32<<<1, 128, 0, stream>>>((unsigned int*)bnsum, 128);
    bn_stats<<<(NN + 511) / 512, 256, 0, stream>>>(hrawA, bnsum);
    bn_final<<<1, 64, 0, stream>>>(bnsum, g0, be0, bnsc);

    // ---- Layer 1 (X transform + JK fused into GEMM staging) ----
    gemm_mfma<64, false, true><<<dim3(gblocks, 1), 256, 0, stream>>>(
        hrawA, Wt1, h_pk, nullptr, nullptr, nullptr, bnsc, jk);
    att_scores<<<(NN + 3) / 4, 256, 0, stream>>>(h_pk, as1, ad1, e_src, e_dst);
    edge_w<<<(NE + 255) / 256, 256, 0, stream>>>(csr_src, csr_dst, e_src, e_dst, walpha);
    aggregate<<<(NN + 3) / 4, 256, 0, stream>>>(offsets, csr_src, walpha, h_pk, hrawA,
                                                bnsc, b1, hrawB);
    zero_u32<<<1, 128, 0, stream>>>((unsigned int*)bnsum, 128);
    bn_stats<<<(NN + 511) / 512, 256, 0, stream>>>(hrawB, bnsum);
    bn_final<<<1, 64, 0, stream>>>(bnsum, g1, be1, bnsc);

    // ---- Layer 2 ----
    gemm_mfma<64, false, true><<<dim3(gblocks, 1), 256, 0, stream>>>(
        hrawB, Wt2, h_pk, nullptr, nullptr, nullptr, bnsc, jk);
    att_scores<<<(NN + 3) / 4, 256, 0, stream>>>(h_pk, as2, ad2, e_src, e_dst);
    edge_w<<<(NE + 255) / 256, 256, 0, stream>>>(csr_src, csr_dst, e_src, e_dst, walpha);
    aggregate<<<(NN + 3) / 4, 256, 0, stream>>>(offsets, csr_src, walpha, h_pk, hrawB,
                                                bnsc, b2, hrawA);
    zero_u32<<<1, 128, 0, stream>>>((unsigned int*)bnsum, 128);
    bn_stats<<<(NN + 511) / 512, 256, 0, stream>>>(hrawA, bnsum);
    bn_final<<<1, 64, 0, stream>>>(bnsum, g2, be2, bnsc);

    final_out<<<(NN * 64 + 255) / 256, 256, 0, stream>>>(hrawA, bnsc, jk, out);
}

// Round 4
// 876.654 us; speedup vs baseline: 1.7123x; 1.1053x over previous
//
#include <hip/hip_runtime.h>

#define NN 100000
#define NE 1600000

constexpr int SCAN_CHUNK = 2048;
constexpr int NB_SCAN = (NN + SCAN_CHUNK - 1) / SCAN_CHUNK;  // 49

typedef __attribute__((ext_vector_type(8))) short s16x8;
typedef __attribute__((ext_vector_type(4))) float f32x4;

__device__ inline unsigned short f2bf(float f) {  // RNE fp32 -> bf16 bits
    unsigned int u = __float_as_uint(f);
    return (unsigned short)((u + 0x7fffu + ((u >> 16) & 1u)) >> 16);
}
__device__ inline float bf_lo(unsigned int pk) { return __uint_as_float(pk << 16); }
__device__ inline float bf_hi(unsigned int pk) { return __uint_as_float(pk & 0xffff0000u); }

__global__ void zero_u32(unsigned int* p, int n) {
    int i = blockIdx.x * blockDim.x + threadIdx.x;
    if (i < n) p[i] = 0u;
}

__global__ void count_deg(const int* __restrict__ dst, int* __restrict__ deg) {
    int i = blockIdx.x * blockDim.x + threadIdx.x;
    if (i < NE) atomicAdd(&deg[dst[i]], 1);
}

__global__ void scan_partial(const int* __restrict__ deg, int* __restrict__ partial) {
    __shared__ int ls[256];
    int base = blockIdx.x * SCAN_CHUNK;
    int t = threadIdx.x;
    int s = 0;
    for (int j = 0; j < SCAN_CHUNK; j += 256) {
        int i = base + j + t;
        if (i < NN) s += deg[i];
    }
    ls[t] = s;
    __syncthreads();
    for (int off = 128; off > 0; off >>= 1) {
        if (t < off) ls[t] += ls[t + off];
        __syncthreads();
    }
    if (t == 0) partial[blockIdx.x] = ls[0];
}

__global__ void scan_serial(int* partial, int* offsets) {
    if (threadIdx.x == 0) {
        int run = 0;
        for (int b = 0; b < NB_SCAN; ++b) {
            int v = partial[b];
            partial[b] = run;
            run += v;
        }
        offsets[NN] = NE;
    }
}

__global__ void scan_final(const int* __restrict__ deg, const int* __restrict__ partial,
                           int* __restrict__ offsets, int* __restrict__ cursor) {
    __shared__ int tot[256];
    int t = threadIdx.x;
    int base = blockIdx.x * SCAN_CHUNK + t * 8;
    int d[8];
    int s = 0;
#pragma unroll
    for (int j = 0; j < 8; ++j) {
        int i = base + j;
        d[j] = (i < NN) ? deg[i] : 0;
        s += d[j];
    }
    tot[t] = s;
    __syncthreads();
    int pre = partial[blockIdx.x];
    for (int j = 0; j < t; ++j) pre += tot[j];
#pragma unroll
    for (int j = 0; j < 8; ++j) {
        int i = base + j;
        if (i < NN) {
            offsets[i] = pre;
            cursor[i] = pre;
        }
        pre += d[j];
    }
}

// Only csr_src is scattered (csr_dst eliminated: weights are computed inside
// aggregate, where dst == the wave's node). Halves the write-allocate traffic.
__global__ void scatter_edges(const int* __restrict__ src, const int* __restrict__ dst,
                              int* __restrict__ cursor, int* __restrict__ csr_src) {
    int i = blockIdx.x * blockDim.x + threadIdx.x;
    if (i < NE) {
        int pos = atomicAdd(&cursor[dst[i]], 1);
        csr_src[pos] = src[i];
    }
}

// Transpose + fp32->bf16 all weights once per launch.
// Wtcat[256][128]: cols(oc) 0..127 = W0, 128..191 = skip0, 192..255 = projW.
__global__ void prep_weights(const float* __restrict__ W0, const float* __restrict__ skip0,
                             const float* __restrict__ projW, const float* __restrict__ W1,
                             const float* __restrict__ W2, unsigned short* __restrict__ Wtcat,
                             unsigned short* __restrict__ Wt1, unsigned short* __restrict__ Wt2) {
    int i = blockIdx.x * 256 + threadIdx.x;
    if (i < 32768) {
        int oc = i >> 7, k = i & 127;
        float v;
        if (oc < 128) v = W0[k * 128 + oc];
        else if (oc < 192) v = skip0[k * 64 + (oc - 128)];
        else v = projW[k * 64 + (oc - 192)];
        Wtcat[oc * 128 + k] = f2bf(v);
    } else if (i < 40960) {
        int j = i - 32768, oc = j >> 6, k = j & 63;
        Wt1[oc * 64 + k] = f2bf(W1[k * 128 + oc]);
    } else if (i < 49152) {
        int j = i - 40960, oc = j >> 6, k = j & 63;
        Wt2[oc * 64 + k] = f2bf(W2[k * 128 + oc]);
    }
}

// MFMA bf16 GEMM: block = 64 rows x 128 cols, 4 waves (wave = 16 rows).
// X fp32 [N][K] staged to LDS bf16 (XFORM: BN+lrelu on the fly + JK max).
// Epilogue (when this block produced h): attention scores e_src/e_dst are
// reduced from the fp32 accumulators (16-lane shuffle) and written packed.
// L0: blockIdx.y==0 -> h + scores; y==1 -> skip (fp32) + proj (+bias).
template <int K, bool L0, bool XFORM>
__global__ __launch_bounds__(256) void gemm_mfma(
    const float* __restrict__ X, const unsigned short* __restrict__ Wt,
    unsigned int* __restrict__ Hpk, float* __restrict__ skipx, float* __restrict__ jkproj,
    const float* __restrict__ projb, const float* __restrict__ bnsc,
    float* __restrict__ jkmax, const float* __restrict__ as_v,
    const float* __restrict__ ad_v, unsigned int* __restrict__ e_srcpk,
    float* __restrict__ e_dst) {
    constexpr int KP = K + 8;
    __shared__ unsigned short As[64 * KP];
    __shared__ unsigned short Bs[128 * KP];
    int t = threadIdx.x;
    int rbase = blockIdx.x * 64;
    const unsigned short* Wtg = Wt + (size_t)blockIdx.y * 128 * K;

    for (int i = t; i < 64 * (K / 4); i += 256) {
        int r = i / (K / 4);
        int kq = (i % (K / 4)) * 4;
        int gr = rbase + r;
        float4 v = make_float4(0.f, 0.f, 0.f, 0.f);
        if (gr < NN) {
            v = *(const float4*)&X[(size_t)gr * K + kq];
            if (XFORM) {
                float* vc = (float*)&v;
#pragma unroll
                for (int c = 0; c < 4; ++c) {
                    float val = vc[c] * bnsc[kq + c] + bnsc[64 + kq + c];
                    val = val >= 0.f ? val : 0.01f * val;
                    int idx = gr * 64 + kq + c;
                    jkmax[idx] = fmaxf(jkmax[idx], val);
                    vc[c] = val;
                }
            }
        }
        uint2 u;
        u.x = (unsigned int)f2bf(v.x) | ((unsigned int)f2bf(v.y) << 16);
        u.y = (unsigned int)f2bf(v.z) | ((unsigned int)f2bf(v.w) << 16);
        *(uint2*)&As[r * KP + kq] = u;
    }
    for (int i = t; i < 128 * (K / 8); i += 256) {
        int oc = i / (K / 8);
        int k8 = (i % (K / 8)) * 8;
        uint4 v = *(const uint4*)&Wtg[(size_t)oc * K + k8];
        *(uint4*)&Bs[oc * KP + k8] = v;
    }
    __syncthreads();

    int lane = t & 63, wv = t >> 6;
    int lr = lane & 15, quad = lane >> 4;
    int arow = wv * 16 + lr;
    f32x4 acc[8];
#pragma unroll
    for (int c = 0; c < 8; ++c) acc[c] = (f32x4)(0.f);
#pragma unroll
    for (int k0 = 0; k0 < K; k0 += 32) {
        s16x8 a = *(const s16x8*)&As[arow * KP + k0 + quad * 8];
#pragma unroll
        for (int ct = 0; ct < 8; ++ct) {
            s16x8 b = *(const s16x8*)&Bs[(ct * 16 + lr) * KP + k0 + quad * 8];
            acc[ct] = __builtin_amdgcn_mfma_f32_16x16x32_bf16(a, b, acc[ct], 0, 0, 0);
        }
    }

    bool hblock = (!L0) || (blockIdx.y == 0);
#pragma unroll
    for (int reg = 0; reg < 4; ++reg) {
        int row = rbase + wv * 16 + quad * 4 + reg;
        if (hblock) {
            // h write (packed bf16 x 2 heads)
            if (row < NN) {
#pragma unroll
                for (int ct = 0; ct < 4; ++ct) {
                    unsigned int pk = (unsigned int)f2bf(acc[ct][reg]) |
                                      ((unsigned int)f2bf(acc[ct + 4][reg]) << 16);
                    Hpk[(size_t)row * 64 + ct * 16 + lr] = pk;
                }
            }
            // attention scores from fp32 acc: reduce over lr (16 lanes)
            float s0 = 0.f, s1 = 0.f, d0 = 0.f, d1 = 0.f;
#pragma unroll
            for (int ct = 0; ct < 4; ++ct) {
                int c = ct * 16 + lr;
                float hlo = acc[ct][reg], hhi = acc[ct + 4][reg];
                s0 += hlo * as_v[c];
                s1 += hhi * as_v[64 + c];
                d0 += hlo * ad_v[c];
                d1 += hhi * ad_v[64 + c];
            }
#pragma unroll
            for (int off = 1; off < 16; off <<= 1) {
                s0 += __shfl_xor(s0, off, 64);
                s1 += __shfl_xor(s1, off, 64);
                d0 += __shfl_xor(d0, off, 64);
                d1 += __shfl_xor(d1, off, 64);
            }
            if (lr == 0 && row < NN) {
                e_srcpk[row] = (unsigned int)f2bf(s0) | ((unsigned int)f2bf(s1) << 16);
                *(float2*)&e_dst[row * 2] = make_float2(d0, d1);
            }
        } else if (row < NN) {
#pragma unroll
            for (int ct = 0; ct < 4; ++ct)
                skipx[(size_t)row * 64 + ct * 16 + lr] = acc[ct][reg];
#pragma unroll
            for (int ct = 4; ct < 8; ++ct) {
                int c = (ct - 4) * 16 + lr;
                jkproj[(size_t)row * 64 + c] = acc[ct][reg] + projb[c];
            }
        }
    }
}

// One wave per destination node. Per edge: uniform csr_src + uniform packed
// e_src + one 4B packed-bf16 h gather per lane; weights computed in-loop.
__global__ __launch_bounds__(256) void aggregate(
    const int* __restrict__ offsets, const int* __restrict__ csr_src,
    const unsigned int* __restrict__ e_srcpk, const float* __restrict__ e_dst,
    const unsigned int* __restrict__ Hpk, const float* __restrict__ skipsrc,
    const float* __restrict__ bnsc, const float* __restrict__ bias,
    float* __restrict__ hraw) {
    int wave = threadIdx.x >> 6;
    int lane = threadIdx.x & 63;
    int n = blockIdx.x * 4 + wave;
    if (n >= NN) return;
    int beg = offsets[n], end = offsets[n + 1];
    float2 ed = *(const float2*)&e_dst[n * 2];
    float acc0 = 0.f, acc1 = 0.f, den0 = 0.f, den1 = 0.f;
    int j = beg;
    for (; j + 1 < end; j += 2) {
        int s0 = csr_src[j];
        int s1 = csr_src[j + 1];
        unsigned int q0 = e_srcpk[s0];
        unsigned int q1 = e_srcpk[s1];
        unsigned int p0 = Hpk[(size_t)s0 * 64 + lane];
        unsigned int p1 = Hpk[(size_t)s1 * 64 + lane];
        float a00 = bf_lo(q0) + ed.x, a01 = bf_hi(q0) + ed.y;
        float a10 = bf_lo(q1) + ed.x, a11 = bf_hi(q1) + ed.y;
        a00 = a00 >= 0.f ? a00 : 0.2f * a00;
        a01 = a01 >= 0.f ? a01 : 0.2f * a01;
        a10 = a10 >= 0.f ? a10 : 0.2f * a10;
        a11 = a11 >= 0.f ? a11 : 0.2f * a11;
        float w00 = __expf(a00), w01 = __expf(a01);
        float w10 = __expf(a10), w11 = __expf(a11);
        den0 += w00 + w10;
        den1 += w01 + w11;
        acc0 += w00 * bf_lo(p0) + w10 * bf_lo(p1);
        acc1 += w01 * bf_hi(p0) + w11 * bf_hi(p1);
    }
    if (j < end) {
        int s0 = csr_src[j];
        unsigned int q0 = e_srcpk[s0];
        unsigned int p0 = Hpk[(size_t)s0 * 64 + lane];
        float a00 = bf_lo(q0) + ed.x, a01 = bf_hi(q0) + ed.y;
        a00 = a00 >= 0.f ? a00 : 0.2f * a00;
        a01 = a01 >= 0.f ? a01 : 0.2f * a01;
        float w00 = __expf(a00), w01 = __expf(a01);
        den0 += w00;
        den1 += w01;
        acc0 += w00 * bf_lo(p0);
        acc1 += w01 * bf_hi(p0);
    }
    float sv = skipsrc[(size_t)n * 64 + lane];
    if (bnsc) {  // identity skip from previous layer's pre-BN buffer
        sv = sv * bnsc[lane] + bnsc[64 + lane];
        sv = sv >= 0.f ? sv : 0.01f * sv;
    }
    float o = 0.5f * (acc0 / (den0 + 1e-16f) + acc1 / (den1 + 1e-16f)) + bias[lane] + sv;
    hraw[(size_t)n * 64 + lane] = o;
}

__global__ void bn_stats(const float* __restrict__ x, float* __restrict__ sums) {
    __shared__ float ls[256], ls2[256];
    int t = threadIdx.x;
    int c = t & 63, q = t >> 6;
    float s = 0.f, s2 = 0.f;
    int rbeg = blockIdx.x * 512;
    for (int r = rbeg + q; r < rbeg + 512; r += 4) {
        if (r < NN) {
            float v = x[(size_t)r * 64 + c];
            s += v;
            s2 += v * v;
        }
    }
    ls[t] = s;
    ls2[t] = s2;
    __syncthreads();
    if (t < 64) {
        s = ls[t] + ls[t + 64] + ls[t + 128] + ls[t + 192];
        s2 = ls2[t] + ls2[t + 64] + ls2[t + 128] + ls2[t + 192];
        atomicAdd(&sums[c], s);
        atomicAdd(&sums[64 + c], s2);
    }
}

__global__ void bn_final(const float* __restrict__ sums, const float* __restrict__ g,
                         const float* __restrict__ be, float* __restrict__ sc_sh) {
    int c = threadIdx.x;
    if (c < 64) {
        float mu = sums[c] / (float)NN;
        float var = sums[64 + c] / (float)NN - mu * mu;
        float sc = g[c] * rsqrtf(var + 1e-5f);
        sc_sh[c] = sc;
        sc_sh[64 + c] = be[c] - mu * sc;
    }
}

__global__ void final_out(const float* __restrict__ hraw, const float* __restrict__ sc_sh,
                          const float* __restrict__ jk, float* __restrict__ out) {
    int i = blockIdx.x * blockDim.x + threadIdx.x;
    if (i < NN * 64) {
        int c = i & 63;
        float v = hraw[i] * sc_sh[c] + sc_sh[64 + c];
        v = v >= 0.f ? v : 0.01f * v;
        out[i] = fmaxf(jk[i], v);
    }
}

extern "C" void kernel_launch(void* const* d_in, const int* in_sizes, int n_in,
                              void* d_out, int out_size, void* d_ws, size_t ws_size,
                              hipStream_t stream) {
    const float* x = (const float*)d_in[0];
    const int* ei = (const int*)d_in[1];
    const int* e_src_idx = ei;
    const int* e_dst_idx = ei + NE;
    const float* W0 = (const float*)d_in[2];
    const float* as0 = (const float*)d_in[3];
    const float* ad0 = (const float*)d_in[4];
    const float* b0 = (const float*)d_in[5];
    const float* skip0 = (const float*)d_in[6];
    const float* g0 = (const float*)d_in[7];
    const float* be0 = (const float*)d_in[8];
    const float* W1 = (const float*)d_in[9];
    const float* as1 = (const float*)d_in[10];
    const float* ad1 = (const float*)d_in[11];
    const float* b1 = (const float*)d_in[12];
    const float* g1 = (const float*)d_in[13];
    const float* be1 = (const float*)d_in[14];
    const float* W2 = (const float*)d_in[15];
    const float* as2 = (const float*)d_in[16];
    const float* ad2 = (const float*)d_in[17];
    const float* b2 = (const float*)d_in[18];
    const float* g2 = (const float*)d_in[19];
    const float* be2 = (const float*)d_in[20];
    const float* projW = (const float*)d_in[21];
    const float* projb = (const float*)d_in[22];
    float* out = (float*)d_out;

    char* p = (char*)d_ws;
    auto alloc = [&](size_t bytes) {
        char* r = p;
        p += (bytes + 255) & ~(size_t)255;
        return r;
    };
    int* deg = (int*)alloc((size_t)NN * 4);  // reused as scatter cursor
    int* offsets = (int*)alloc((size_t)(NN + 1) * 4);
    int* partial = (int*)alloc((size_t)NB_SCAN * 4);
    int* csr_src = (int*)alloc((size_t)NE * 4);
    unsigned int* h_pk = (unsigned int*)alloc((size_t)NN * 64 * 4);
    unsigned int* e_srcpk = (unsigned int*)alloc((size_t)NN * 4);
    float* e_dst = (float*)alloc((size_t)NN * 2 * 4);
    float* skipx = (float*)alloc((size_t)NN * 64 * 4);
    float* jk = (float*)alloc((size_t)NN * 64 * 4);
    float* hrawA = (float*)alloc((size_t)NN * 64 * 4);
    float* hrawB = (float*)alloc((size_t)NN * 64 * 4);
    unsigned short* Wtcat = (unsigned short*)alloc(256 * 128 * 2);
    unsigned short* Wt1 = (unsigned short*)alloc(128 * 64 * 2);
    unsigned short* Wt2 = (unsigned short*)alloc(128 * 64 * 2);
    float* bnsum = (float*)alloc(128 * 4);
    float* bnsc = (float*)alloc(128 * 4);
    if ((size_t)(p - (char*)d_ws) > ws_size) return;

    // ---- CSR by destination + weight prep ----
    zero_u32<<<(NN + 255) / 256, 256, 0, stream>>>((unsigned int*)deg, NN);
    count_deg<<<(NE + 255) / 256, 256, 0, stream>>>(e_dst_idx, deg);
    scan_partial<<<NB_SCAN, 256, 0, stream>>>(deg, partial);
    scan_serial<<<1, 64, 0, stream>>>(partial, offsets);
    scan_final<<<NB_SCAN, 256, 0, stream>>>(deg, partial, offsets, deg);
    scatter_edges<<<(NE + 255) / 256, 256, 0, stream>>>(e_src_idx, e_dst_idx, deg, csr_src);
    prep_weights<<<192, 256, 0, stream>>>(W0, skip0, projW, W1, W2, Wtcat, Wt1, Wt2);

    int gblocks = (NN + 63) / 64;  // 1563

    // ---- Layer 0 (one GEMM: h+scores | skip+proj) ----
    gemm_mfma<128, true, false><<<dim3(gblocks, 2), 256, 0, stream>>>(
        x, Wtcat, h_pk, skipx, jk, projb, nullptr, nullptr, as0, ad0, e_srcpk, e_dst);
    aggregate<<<(NN + 3) / 4, 256, 0, stream>>>(offsets, csr_src, e_srcpk, e_dst, h_pk,
                                                skipx, nullptr, b0, hrawA);
    zero_u32<<<1, 128, 0, stream>>>((unsigned int*)bnsum, 128);
    bn_stats<<<(NN + 511) / 512, 256, 0, stream>>>(hrawA, bnsum);
    bn_final<<<1, 64, 0, stream>>>(bnsum, g0, be0, bnsc);

    // ---- Layer 1 ----
    gemm_mfma<64, false, true><<<dim3(gblocks, 1), 256, 0, stream>>>(
        hrawA, Wt1, h_pk, nullptr, nullptr, nullptr, bnsc, jk, as1, ad1, e_srcpk, e_dst);
    aggregate<<<(NN + 3) / 4, 256, 0, stream>>>(offsets, csr_src, e_srcpk, e_dst, h_pk,
                                                hrawA, bnsc, b1, hrawB);
    zero_u32<<<1, 128, 0, stream>>>((unsigned int*)bnsum, 128);
    bn_stats<<<(NN + 511) / 512, 256, 0, stream>>>(hrawB, bnsum);
    bn_final<<<1, 64, 0, stream>>>(bnsum, g1, be1, bnsc);

    // ---- Layer 2 ----
    gemm_mfma<64, false, true><<<dim3(gblocks, 1), 256, 0, stream>>>(
        hrawB, Wt2, h_pk, nullptr, nullptr, nullptr, bnsc, jk, as2, ad2, e_srcpk, e_dst);
    aggregate<<<(NN + 3) / 4, 256, 0, stream>>>(offsets, csr_src, e_srcpk, e_dst, h_pk,
                                                hrawB, bnsc, b2, hrawA);
    zero_u32<<<1, 128, 0, stream>>>((unsigned int*)bnsum, 128);
    bn_stats<<<(NN + 511) / 512, 256, 0, stream>>>(hrawA, bnsum);
    bn_final<<<1, 64, 0, stream>>>(bnsum, g2, be2, bnsc);

    final_out<<<(NN * 64 + 255) / 256, 256, 0, stream>>>(hrawA, bnsc, jk, out);
}

// Round 5
// 831.485 us; speedup vs baseline: 1.8053x; 1.0543x over previous
//
#include <hip/hip_runtime.h>

#define NN 100000
#define NE 1600000

constexpr int SCAN_CHUNK = 2048;
constexpr int NB_SCAN = (NN + SCAN_CHUNK - 1) / SCAN_CHUNK;  // 49
constexpr int NBUC = 196;       // bucket = dst >> 9 (512 nodes/bucket)
constexpr int BIN_CHUNK = 4096;
constexpr int NB_BIN = (NE + BIN_CHUNK - 1) / BIN_CHUNK;  // 391

typedef __attribute__((ext_vector_type(8))) short s16x8;
typedef __attribute__((ext_vector_type(4))) float f32x4;

__device__ inline unsigned short f2bf(float f) {  // RNE fp32 -> bf16 bits
    unsigned int u = __float_as_uint(f);
    return (unsigned short)((u + 0x7fffu + ((u >> 16) & 1u)) >> 16);
}
__device__ inline float bf_lo(unsigned int pk) { return __uint_as_float(pk << 16); }
__device__ inline float bf_hi(unsigned int pk) { return __uint_as_float(pk & 0xffff0000u); }

__global__ void zero_u32(unsigned int* p, int n) {
    int i = blockIdx.x * blockDim.x + threadIdx.x;
    if (i < n) p[i] = 0u;
}

__global__ void count_deg(const int* __restrict__ dst, int* __restrict__ deg) {
    int i = blockIdx.x * blockDim.x + threadIdx.x;
    if (i < NE) atomicAdd(&deg[dst[i]], 1);
}

__global__ void scan_partial(const int* __restrict__ deg, int* __restrict__ partial) {
    __shared__ int ls[256];
    int base = blockIdx.x * SCAN_CHUNK;
    int t = threadIdx.x;
    int s = 0;
    for (int j = 0; j < SCAN_CHUNK; j += 256) {
        int i = base + j + t;
        if (i < NN) s += deg[i];
    }
    ls[t] = s;
    __syncthreads();
    for (int off = 128; off > 0; off >>= 1) {
        if (t < off) ls[t] += ls[t + off];
        __syncthreads();
    }
    if (t == 0) partial[blockIdx.x] = ls[0];
}

__global__ void scan_serial(int* partial, int* offsets) {
    if (threadIdx.x == 0) {
        int run = 0;
        for (int b = 0; b < NB_SCAN; ++b) {
            int v = partial[b];
            partial[b] = run;
            run += v;
        }
        offsets[NN] = NE;
    }
}

__global__ void scan_final(const int* __restrict__ deg, const int* __restrict__ partial,
                           int* __restrict__ offsets, int* __restrict__ cursor) {
    __shared__ int tot[256];
    int t = threadIdx.x;
    int base = blockIdx.x * SCAN_CHUNK + t * 8;
    int d[8];
    int s = 0;
#pragma unroll
    for (int j = 0; j < 8; ++j) {
        int i = base + j;
        d[j] = (i < NN) ? deg[i] : 0;
        s += d[j];
    }
    tot[t] = s;
    __syncthreads();
    int pre = partial[blockIdx.x];
    for (int j = 0; j < t; ++j) pre += tot[j];
#pragma unroll
    for (int j = 0; j < 8; ++j) {
        int i = base + j;
        if (i < NN) {
            offsets[i] = pre;
            cursor[i] = pre;
        }
        pre += d[j];
    }
}

__global__ void bucket_init(const int* __restrict__ offsets, int* __restrict__ bucket_cursor) {
    int b = blockIdx.x * blockDim.x + threadIdx.x;
    if (b < NBUC) bucket_cursor[b] = offsets[b << 9];
}

// Pass A of binned CSR build: per-block LDS histogram over dst buckets,
// per-bucket chunk reservation (global atomic), then bucket-major (src,dst)
// writes in contiguous runs -> near-full-line HBM writes.
__global__ __launch_bounds__(256) void bin_edges(const int* __restrict__ src,
                                                 const int* __restrict__ dst,
                                                 int* __restrict__ bucket_cursor,
                                                 uint2* __restrict__ binned) {
    __shared__ int hist[NBUC];
    __shared__ int base[NBUC];
    int t = threadIdx.x;
    for (int b = t; b < NBUC; b += 256) hist[b] = 0;
    __syncthreads();
    int beg = blockIdx.x * BIN_CHUNK;
    int end = min(beg + BIN_CHUNK, NE);
    for (int i = beg + t; i < end; i += 256) atomicAdd(&hist[dst[i] >> 9], 1);
    __syncthreads();
    for (int b = t; b < NBUC; b += 256) {
        base[b] = atomicAdd(&bucket_cursor[b], hist[b]);
        hist[b] = 0;
    }
    __syncthreads();
    for (int i = beg + t; i < end; i += 256) {
        int d = dst[i];
        int bk = d >> 9;
        int loc = atomicAdd(&hist[bk], 1);
        binned[base[bk] + loc] = make_uint2((unsigned)src[i], (unsigned)d);
    }
}

// Pass B: stream bucket-major edges; csr writes for one node's row now arrive
// temporally clustered (within one ~16KB bucket span) -> lines fill in L2.
__global__ void scatter_local(const uint2* __restrict__ binned, int* __restrict__ cursor,
                              int* __restrict__ csr_src) {
    int i = blockIdx.x * blockDim.x + threadIdx.x;
    if (i < NE) {
        uint2 e = binned[i];
        int pos = atomicAdd(&cursor[e.y], 1);
        csr_src[pos] = (int)e.x;
    }
}

// Transpose + fp32->bf16 all weights once per launch.
// Wtcat[256][128]: cols(oc) 0..127 = W0, 128..191 = skip0, 192..255 = projW.
__global__ void prep_weights(const float* __restrict__ W0, const float* __restrict__ skip0,
                             const float* __restrict__ projW, const float* __restrict__ W1,
                             const float* __restrict__ W2, unsigned short* __restrict__ Wtcat,
                             unsigned short* __restrict__ Wt1, unsigned short* __restrict__ Wt2) {
    int i = blockIdx.x * 256 + threadIdx.x;
    if (i < 32768) {
        int oc = i >> 7, k = i & 127;
        float v;
        if (oc < 128) v = W0[k * 128 + oc];
        else if (oc < 192) v = skip0[k * 64 + (oc - 128)];
        else v = projW[k * 64 + (oc - 192)];
        Wtcat[oc * 128 + k] = f2bf(v);
    } else if (i < 40960) {
        int j = i - 32768, oc = j >> 6, k = j & 63;
        Wt1[oc * 64 + k] = f2bf(W1[k * 128 + oc]);
    } else if (i < 49152) {
        int j = i - 40960, oc = j >> 6, k = j & 63;
        Wt2[oc * 64 + k] = f2bf(W2[k * 128 + oc]);
    }
}

// MFMA bf16 GEMM: block = 64 rows x 128 cols, 4 waves (wave = 16 rows).
// X fp32 [N][K] staged to LDS bf16 (XFORM: BN+lrelu on the fly + JK max).
// Epilogue (h blocks): attention scores reduced from fp32 accumulators.
// L0: blockIdx.y==0 -> h + scores; y==1 -> skip (fp32) + proj (+bias).
template <int K, bool L0, bool XFORM>
__global__ __launch_bounds__(256) void gemm_mfma(
    const float* __restrict__ X, const unsigned short* __restrict__ Wt,
    unsigned int* __restrict__ Hpk, float* __restrict__ skipx, float* __restrict__ jkproj,
    const float* __restrict__ projb, const float* __restrict__ bnsc,
    float* __restrict__ jkmax, const float* __restrict__ as_v,
    const float* __restrict__ ad_v, unsigned int* __restrict__ e_srcpk,
    float* __restrict__ e_dst) {
    constexpr int KP = K + 8;
    __shared__ unsigned short As[64 * KP];
    __shared__ unsigned short Bs[128 * KP];
    int t = threadIdx.x;
    int rbase = blockIdx.x * 64;
    const unsigned short* Wtg = Wt + (size_t)blockIdx.y * 128 * K;

    for (int i = t; i < 64 * (K / 4); i += 256) {
        int r = i / (K / 4);
        int kq = (i % (K / 4)) * 4;
        int gr = rbase + r;
        float4 v = make_float4(0.f, 0.f, 0.f, 0.f);
        if (gr < NN) {
            v = *(const float4*)&X[(size_t)gr * K + kq];
            if (XFORM) {
                float* vc = (float*)&v;
#pragma unroll
                for (int c = 0; c < 4; ++c) {
                    float val = vc[c] * bnsc[kq + c] + bnsc[64 + kq + c];
                    val = val >= 0.f ? val : 0.01f * val;
                    int idx = gr * 64 + kq + c;
                    jkmax[idx] = fmaxf(jkmax[idx], val);
                    vc[c] = val;
                }
            }
        }
        uint2 u;
        u.x = (unsigned int)f2bf(v.x) | ((unsigned int)f2bf(v.y) << 16);
        u.y = (unsigned int)f2bf(v.z) | ((unsigned int)f2bf(v.w) << 16);
        *(uint2*)&As[r * KP + kq] = u;
    }
    for (int i = t; i < 128 * (K / 8); i += 256) {
        int oc = i / (K / 8);
        int k8 = (i % (K / 8)) * 8;
        uint4 v = *(const uint4*)&Wtg[(size_t)oc * K + k8];
        *(uint4*)&Bs[oc * KP + k8] = v;
    }
    __syncthreads();

    int lane = t & 63, wv = t >> 6;
    int lr = lane & 15, quad = lane >> 4;
    int arow = wv * 16 + lr;
    f32x4 acc[8];
#pragma unroll
    for (int c = 0; c < 8; ++c) acc[c] = (f32x4)(0.f);
#pragma unroll
    for (int k0 = 0; k0 < K; k0 += 32) {
        s16x8 a = *(const s16x8*)&As[arow * KP + k0 + quad * 8];
#pragma unroll
        for (int ct = 0; ct < 8; ++ct) {
            s16x8 b = *(const s16x8*)&Bs[(ct * 16 + lr) * KP + k0 + quad * 8];
            acc[ct] = __builtin_amdgcn_mfma_f32_16x16x32_bf16(a, b, acc[ct], 0, 0, 0);
        }
    }

    bool hblock = (!L0) || (blockIdx.y == 0);
#pragma unroll
    for (int reg = 0; reg < 4; ++reg) {
        int row = rbase + wv * 16 + quad * 4 + reg;
        if (hblock) {
            if (row < NN) {
#pragma unroll
                for (int ct = 0; ct < 4; ++ct) {
                    unsigned int pk = (unsigned int)f2bf(acc[ct][reg]) |
                                      ((unsigned int)f2bf(acc[ct + 4][reg]) << 16);
                    Hpk[(size_t)row * 64 + ct * 16 + lr] = pk;
                }
            }
            float s0 = 0.f, s1 = 0.f, d0 = 0.f, d1 = 0.f;
#pragma unroll
            for (int ct = 0; ct < 4; ++ct) {
                int c = ct * 16 + lr;
                float hlo = acc[ct][reg], hhi = acc[ct + 4][reg];
                s0 += hlo * as_v[c];
                s1 += hhi * as_v[64 + c];
                d0 += hlo * ad_v[c];
                d1 += hhi * ad_v[64 + c];
            }
#pragma unroll
            for (int off = 1; off < 16; off <<= 1) {
                s0 += __shfl_xor(s0, off, 64);
                s1 += __shfl_xor(s1, off, 64);
                d0 += __shfl_xor(d0, off, 64);
                d1 += __shfl_xor(d1, off, 64);
            }
            if (lr == 0 && row < NN) {
                e_srcpk[row] = (unsigned int)f2bf(s0) | ((unsigned int)f2bf(s1) << 16);
                *(float2*)&e_dst[row * 2] = make_float2(d0, d1);
            }
        } else if (row < NN) {
#pragma unroll
            for (int ct = 0; ct < 4; ++ct)
                skipx[(size_t)row * 64 + ct * 16 + lr] = acc[ct][reg];
#pragma unroll
            for (int ct = 4; ct < 8; ++ct) {
                int c = (ct - 4) * 16 + lr;
                jkproj[(size_t)row * 64 + c] = acc[ct][reg] + projb[c];
            }
        }
    }
}

// One wave per destination node. Per edge: uniform csr_src + uniform packed
// e_src + one 4B packed-bf16 h gather per lane; weights computed in-loop.
__global__ __launch_bounds__(256) void aggregate(
    const int* __restrict__ offsets, const int* __restrict__ csr_src,
    const unsigned int* __restrict__ e_srcpk, const float* __restrict__ e_dst,
    const unsigned int* __restrict__ Hpk, const float* __restrict__ skipsrc,
    const float* __restrict__ bnsc, const float* __restrict__ bias,
    float* __restrict__ hraw) {
    int wave = threadIdx.x >> 6;
    int lane = threadIdx.x & 63;
    int n = blockIdx.x * 4 + wave;
    if (n >= NN) return;
    int beg = offsets[n], end = offsets[n + 1];
    float2 ed = *(const float2*)&e_dst[n * 2];
    float acc0 = 0.f, acc1 = 0.f, den0 = 0.f, den1 = 0.f;
    int j = beg;
    for (; j + 1 < end; j += 2) {
        int s0 = csr_src[j];
        int s1 = csr_src[j + 1];
        unsigned int q0 = e_srcpk[s0];
        unsigned int q1 = e_srcpk[s1];
        unsigned int p0 = Hpk[(size_t)s0 * 64 + lane];
        unsigned int p1 = Hpk[(size_t)s1 * 64 + lane];
        float a00 = bf_lo(q0) + ed.x, a01 = bf_hi(q0) + ed.y;
        float a10 = bf_lo(q1) + ed.x, a11 = bf_hi(q1) + ed.y;
        a00 = a00 >= 0.f ? a00 : 0.2f * a00;
        a01 = a01 >= 0.f ? a01 : 0.2f * a01;
        a10 = a10 >= 0.f ? a10 : 0.2f * a10;
        a11 = a11 >= 0.f ? a11 : 0.2f * a11;
        float w00 = __expf(a00), w01 = __expf(a01);
        float w10 = __expf(a10), w11 = __expf(a11);
        den0 += w00 + w10;
        den1 += w01 + w11;
        acc0 += w00 * bf_lo(p0) + w10 * bf_lo(p1);
        acc1 += w01 * bf_hi(p0) + w11 * bf_hi(p1);
    }
    if (j < end) {
        int s0 = csr_src[j];
        unsigned int q0 = e_srcpk[s0];
        unsigned int p0 = Hpk[(size_t)s0 * 64 + lane];
        float a00 = bf_lo(q0) + ed.x, a01 = bf_hi(q0) + ed.y;
        a00 = a00 >= 0.f ? a00 : 0.2f * a00;
        a01 = a01 >= 0.f ? a01 : 0.2f * a01;
        float w00 = __expf(a00), w01 = __expf(a01);
        den0 += w00;
        den1 += w01;
        acc0 += w00 * bf_lo(p0);
        acc1 += w01 * bf_hi(p0);
    }
    float sv = skipsrc[(size_t)n * 64 + lane];
    if (bnsc) {  // identity skip from previous layer's pre-BN buffer
        sv = sv * bnsc[lane] + bnsc[64 + lane];
        sv = sv >= 0.f ? sv : 0.01f * sv;
    }
    float o = 0.5f * (acc0 / (den0 + 1e-16f) + acc1 / (den1 + 1e-16f)) + bias[lane] + sv;
    hraw[(size_t)n * 64 + lane] = o;
}

__global__ void bn_stats(const float* __restrict__ x, float* __restrict__ sums) {
    __shared__ float ls[256], ls2[256];
    int t = threadIdx.x;
    int c = t & 63, q = t >> 6;
    float s = 0.f, s2 = 0.f;
    int rbeg = blockIdx.x * 512;
    for (int r = rbeg + q; r < rbeg + 512; r += 4) {
        if (r < NN) {
            float v = x[(size_t)r * 64 + c];
            s += v;
            s2 += v * v;
        }
    }
    ls[t] = s;
    ls2[t] = s2;
    __syncthreads();
    if (t < 64) {
        s = ls[t] + ls[t + 64] + ls[t + 128] + ls[t + 192];
        s2 = ls2[t] + ls2[t + 64] + ls2[t + 128] + ls2[t + 192];
        atomicAdd(&sums[c], s);
        atomicAdd(&sums[64 + c], s2);
    }
}

__global__ void bn_final(const float* __restrict__ sums, const float* __restrict__ g,
                         const float* __restrict__ be, float* __restrict__ sc_sh) {
    int c = threadIdx.x;
    if (c < 64) {
        float mu = sums[c] / (float)NN;
        float var = sums[64 + c] / (float)NN - mu * mu;
        float sc = g[c] * rsqrtf(var + 1e-5f);
        sc_sh[c] = sc;
        sc_sh[64 + c] = be[c] - mu * sc;
    }
}

__global__ void final_out(const float* __restrict__ hraw, const float* __restrict__ sc_sh,
                          const float* __restrict__ jk, float* __restrict__ out) {
    int i = blockIdx.x * blockDim.x + threadIdx.x;
    if (i < NN * 64) {
        int c = i & 63;
        float v = hraw[i] * sc_sh[c] + sc_sh[64 + c];
        v = v >= 0.f ? v : 0.01f * v;
        out[i] = fmaxf(jk[i], v);
    }
}

extern "C" void kernel_launch(void* const* d_in, const int* in_sizes, int n_in,
                              void* d_out, int out_size, void* d_ws, size_t ws_size,
                              hipStream_t stream) {
    const float* x = (const float*)d_in[0];
    const int* ei = (const int*)d_in[1];
    const int* e_src_idx = ei;
    const int* e_dst_idx = ei + NE;
    const float* W0 = (const float*)d_in[2];
    const float* as0 = (const float*)d_in[3];
    const float* ad0 = (const float*)d_in[4];
    const float* b0 = (const float*)d_in[5];
    const float* skip0 = (const float*)d_in[6];
    const float* g0 = (const float*)d_in[7];
    const float* be0 = (const float*)d_in[8];
    const float* W1 = (const float*)d_in[9];
    const float* as1 = (const float*)d_in[10];
    const float* ad1 = (const float*)d_in[11];
    const float* b1 = (const float*)d_in[12];
    const float* g1 = (const float*)d_in[13];
    const float* be1 = (const float*)d_in[14];
    const float* W2 = (const float*)d_in[15];
    const float* as2 = (const float*)d_in[16];
    const float* ad2 = (const float*)d_in[17];
    const float* b2 = (const float*)d_in[18];
    const float* g2 = (const float*)d_in[19];
    const float* be2 = (const float*)d_in[20];
    const float* projW = (const float*)d_in[21];
    const float* projb = (const float*)d_in[22];
    float* out = (float*)d_out;

    char* p = (char*)d_ws;
    auto alloc = [&](size_t bytes) {
        char* r = p;
        p += (bytes + 255) & ~(size_t)255;
        return r;
    };
    int* deg = (int*)alloc((size_t)NN * 4);  // reused as scatter cursor
    int* offsets = (int*)alloc((size_t)(NN + 1) * 4);
    int* partial = (int*)alloc((size_t)NB_SCAN * 4);
    int* bucket_cursor = (int*)alloc((size_t)NBUC * 4);
    int* csr_src = (int*)alloc((size_t)NE * 4);
    uint2* binned = (uint2*)alloc((size_t)NE * 8);
    unsigned int* h_pk = (unsigned int*)alloc((size_t)NN * 64 * 4);
    unsigned int* e_srcpk = (unsigned int*)alloc((size_t)NN * 4);
    float* e_dst = (float*)alloc((size_t)NN * 2 * 4);
    float* skipx = (float*)alloc((size_t)NN * 64 * 4);
    float* jk = (float*)alloc((size_t)NN * 64 * 4);
    float* hrawA = (float*)alloc((size_t)NN * 64 * 4);
    float* hrawB = (float*)alloc((size_t)NN * 64 * 4);
    unsigned short* Wtcat = (unsigned short*)alloc(256 * 128 * 2);
    unsigned short* Wt1 = (unsigned short*)alloc(128 * 64 * 2);
    unsigned short* Wt2 = (unsigned short*)alloc(128 * 64 * 2);
    float* bnsumAll = (float*)alloc(3 * 128 * 4);
    float* bnsc = (float*)alloc(128 * 4);
    if ((size_t)(p - (char*)d_ws) > ws_size) return;

    // ---- CSR by destination (binned two-pass) + weight prep ----
    zero_u32<<<(NN + 255) / 256, 256, 0, stream>>>((unsigned int*)deg, NN);
    zero_u32<<<2, 256, 0, stream>>>((unsigned int*)bnsumAll, 3 * 128);
    count_deg<<<(NE + 255) / 256, 256, 0, stream>>>(e_dst_idx, deg);
    scan_partial<<<NB_SCAN, 256, 0, stream>>>(deg, partial);
    scan_serial<<<1, 64, 0, stream>>>(partial, offsets);
    scan_final<<<NB_SCAN, 256, 0, stream>>>(deg, partial, offsets, deg);
    bucket_init<<<1, 256, 0, stream>>>(offsets, bucket_cursor);
    bin_edges<<<NB_BIN, 256, 0, stream>>>(e_src_idx, e_dst_idx, bucket_cursor, binned);
    scatter_local<<<(NE + 255) / 256, 256, 0, stream>>>(binned, deg, csr_src);
    prep_weights<<<192, 256, 0, stream>>>(W0, skip0, projW, W1, W2, Wtcat, Wt1, Wt2);

    int gblocks = (NN + 63) / 64;  // 1563

    // ---- Layer 0 (one GEMM: h+scores | skip+proj) ----
    gemm_mfma<128, true, false><<<dim3(gblocks, 2), 256, 0, stream>>>(
        x, Wtcat, h_pk, skipx, jk, projb, nullptr, nullptr, as0, ad0, e_srcpk, e_dst);
    aggregate<<<(NN + 3) / 4, 256, 0, stream>>>(offsets, csr_src, e_srcpk, e_dst, h_pk,
                                                skipx, nullptr, b0, hrawA);
    bn_stats<<<(NN + 511) / 512, 256, 0, stream>>>(hrawA, bnsumAll);
    bn_final<<<1, 64, 0, stream>>>(bnsumAll, g0, be0, bnsc);

    // ---- Layer 1 ----
    gemm_mfma<64, false, true><<<dim3(gblocks, 1), 256, 0, stream>>>(
        hrawA, Wt1, h_pk, nullptr, nullptr, nullptr, bnsc, jk, as1, ad1, e_srcpk, e_dst);
    aggregate<<<(NN + 3) / 4, 256, 0, stream>>>(offsets, csr_src, e_srcpk, e_dst, h_pk,
                                                hrawA, bnsc, b1, hrawB);
    bn_stats<<<(NN + 511) / 512, 256, 0, stream>>>(hrawB, bnsumAll + 128);
    bn_final<<<1, 64, 0, stream>>>(bnsumAll + 128, g1, be1, bnsc);

    // ---- Layer 2 ----
    gemm_mfma<64, false, true><<<dim3(gblocks, 1), 256, 0, stream>>>(
        hrawB, Wt2, h_pk, nullptr, nullptr, nullptr, bnsc, jk, as2, ad2, e_srcpk, e_dst);
    aggregate<<<(NN + 3) / 4, 256, 0, stream>>>(offsets, csr_src, e_srcpk, e_dst, h_pk,
                                                hrawB, bnsc, b2, hrawA);
    bn_stats<<<(NN + 511) / 512, 256, 0, stream>>>(hrawA, bnsumAll + 256);
    bn_final<<<1, 64, 0, stream>>>(bnsumAll + 256, g2, be2, bnsc);

    final_out<<<(NN * 64 + 255) / 256, 256, 0, stream>>>(hrawA, bnsc, jk, out);
}

// Round 6
// 766.217 us; speedup vs baseline: 1.9591x; 1.0852x over previous
//
#include <hip/hip_runtime.h>

#define NN 100000
#define NE 1600000

constexpr int SCAN_CHUNK = 2048;
constexpr int NB_SCAN = (NN + SCAN_CHUNK - 1) / SCAN_CHUNK;  // 49
constexpr int NBUC = 196;       // bucket = dst >> 9 (512 nodes/bucket)
constexpr int BIN_CHUNK = 4096;
constexpr int NB_BIN = (NE + BIN_CHUNK - 1) / BIN_CHUNK;  // 391

typedef __attribute__((ext_vector_type(8))) short s16x8;
typedef __attribute__((ext_vector_type(4))) float f32x4;

__device__ inline unsigned short f2bf(float f) {  // RNE fp32 -> bf16 bits
    unsigned int u = __float_as_uint(f);
    return (unsigned short)((u + 0x7fffu + ((u >> 16) & 1u)) >> 16);
}
__device__ inline float bf_lo(unsigned int pk) { return __uint_as_float(pk << 16); }
__device__ inline float bf_hi(unsigned int pk) { return __uint_as_float(pk & 0xffff0000u); }

__global__ void zero_u32(unsigned int* p, int n) {
    int i = blockIdx.x * blockDim.x + threadIdx.x;
    if (i < n) p[i] = 0u;
}

__global__ void count_deg(const int* __restrict__ dst, int* __restrict__ deg) {
    int i = blockIdx.x * blockDim.x + threadIdx.x;
    if (i < NE) atomicAdd(&deg[dst[i]], 1);
}

__global__ void scan_partial(const int* __restrict__ deg, int* __restrict__ partial) {
    __shared__ int ls[256];
    int base = blockIdx.x * SCAN_CHUNK;
    int t = threadIdx.x;
    int s = 0;
    for (int j = 0; j < SCAN_CHUNK; j += 256) {
        int i = base + j + t;
        if (i < NN) s += deg[i];
    }
    ls[t] = s;
    __syncthreads();
    for (int off = 128; off > 0; off >>= 1) {
        if (t < off) ls[t] += ls[t + off];
        __syncthreads();
    }
    if (t == 0) partial[blockIdx.x] = ls[0];
}

__global__ void scan_serial(int* partial, int* offsets) {
    if (threadIdx.x == 0) {
        int run = 0;
        for (int b = 0; b < NB_SCAN; ++b) {
            int v = partial[b];
            partial[b] = run;
            run += v;
        }
        offsets[NN] = NE;
    }
}

__global__ void scan_final(const int* __restrict__ deg, const int* __restrict__ partial,
                           int* __restrict__ offsets, int* __restrict__ cursor) {
    __shared__ int tot[256];
    int t = threadIdx.x;
    int base = blockIdx.x * SCAN_CHUNK + t * 8;
    int d[8];
    int s = 0;
#pragma unroll
    for (int j = 0; j < 8; ++j) {
        int i = base + j;
        d[j] = (i < NN) ? deg[i] : 0;
        s += d[j];
    }
    tot[t] = s;
    __syncthreads();
    int pre = partial[blockIdx.x];
    for (int j = 0; j < t; ++j) pre += tot[j];
#pragma unroll
    for (int j = 0; j < 8; ++j) {
        int i = base + j;
        if (i < NN) {
            offsets[i] = pre;
            cursor[i] = pre;
        }
        pre += d[j];
    }
}

__global__ void bucket_init(const int* __restrict__ offsets, int* __restrict__ bucket_cursor) {
    int b = blockIdx.x * blockDim.x + threadIdx.x;
    if (b < NBUC) bucket_cursor[b] = offsets[b << 9];
}

// Pass A of binned CSR build: per-block LDS histogram over dst buckets,
// per-bucket chunk reservation (global atomic), then bucket-major (src,dst)
// writes in contiguous runs -> near-full-line HBM writes.
__global__ __launch_bounds__(256) void bin_edges(const int* __restrict__ src,
                                                 const int* __restrict__ dst,
                                                 int* __restrict__ bucket_cursor,
                                                 uint2* __restrict__ binned) {
    __shared__ int hist[NBUC];
    __shared__ int base[NBUC];
    int t = threadIdx.x;
    for (int b = t; b < NBUC; b += 256) hist[b] = 0;
    __syncthreads();
    int beg = blockIdx.x * BIN_CHUNK;
    int end = min(beg + BIN_CHUNK, NE);
    for (int i = beg + t; i < end; i += 256) atomicAdd(&hist[dst[i] >> 9], 1);
    __syncthreads();
    for (int b = t; b < NBUC; b += 256) {
        base[b] = atomicAdd(&bucket_cursor[b], hist[b]);
        hist[b] = 0;
    }
    __syncthreads();
    for (int i = beg + t; i < end; i += 256) {
        int d = dst[i];
        int bk = d >> 9;
        int loc = atomicAdd(&hist[bk], 1);
        binned[base[bk] + loc] = make_uint2((unsigned)src[i], (unsigned)d);
    }
}

// Pass B: stream bucket-major edges; csr writes for one node's row arrive
// temporally clustered (one ~16KB bucket span) -> lines fill in L2.
// Writes both csr_src and csr_dst (csr_dst feeds the per-layer edge_w pass).
__global__ void scatter_local(const uint2* __restrict__ binned, int* __restrict__ cursor,
                              int* __restrict__ csr_src, int* __restrict__ csr_dst) {
    int i = blockIdx.x * blockDim.x + threadIdx.x;
    if (i < NE) {
        uint2 e = binned[i];
        int pos = atomicAdd(&cursor[e.y], 1);
        csr_src[pos] = (int)e.x;
        csr_dst[pos] = (int)e.y;
    }
}

// Transpose + fp32->bf16 all weights once per launch.
// Wtcat[256][128]: cols(oc) 0..127 = W0, 128..191 = skip0, 192..255 = projW.
__global__ void prep_weights(const float* __restrict__ W0, const float* __restrict__ skip0,
                             const float* __restrict__ projW, const float* __restrict__ W1,
                             const float* __restrict__ W2, unsigned short* __restrict__ Wtcat,
                             unsigned short* __restrict__ Wt1, unsigned short* __restrict__ Wt2) {
    int i = blockIdx.x * 256 + threadIdx.x;
    if (i < 32768) {
        int oc = i >> 7, k = i & 127;
        float v;
        if (oc < 128) v = W0[k * 128 + oc];
        else if (oc < 192) v = skip0[k * 64 + (oc - 128)];
        else v = projW[k * 64 + (oc - 192)];
        Wtcat[oc * 128 + k] = f2bf(v);
    } else if (i < 40960) {
        int j = i - 32768, oc = j >> 6, k = j & 63;
        Wt1[oc * 64 + k] = f2bf(W1[k * 128 + oc]);
    } else if (i < 49152) {
        int j = i - 40960, oc = j >> 6, k = j & 63;
        Wt2[oc * 64 + k] = f2bf(W2[k * 128 + oc]);
    }
}

// MFMA bf16 GEMM: block = 64 rows x 128 cols, 4 waves (wave = 16 rows).
// X fp32 [N][K] staged to LDS bf16 (XFORM: BN+lrelu on the fly + JK max).
// Epilogue (h blocks): attention scores reduced from fp32 accumulators,
// written as packed bf16x2 (e_srcpk / e_dstpk).
// L0: blockIdx.y==0 -> h + scores; y==1 -> skip (fp32) + proj (+bias).
template <int K, bool L0, bool XFORM>
__global__ __launch_bounds__(256) void gemm_mfma(
    const float* __restrict__ X, const unsigned short* __restrict__ Wt,
    unsigned int* __restrict__ Hpk, float* __restrict__ skipx, float* __restrict__ jkproj,
    const float* __restrict__ projb, const float* __restrict__ bnsc,
    float* __restrict__ jkmax, const float* __restrict__ as_v,
    const float* __restrict__ ad_v, unsigned int* __restrict__ e_srcpk,
    unsigned int* __restrict__ e_dstpk) {
    constexpr int KP = K + 8;
    __shared__ unsigned short As[64 * KP];
    __shared__ unsigned short Bs[128 * KP];
    int t = threadIdx.x;
    int rbase = blockIdx.x * 64;
    const unsigned short* Wtg = Wt + (size_t)blockIdx.y * 128 * K;

    for (int i = t; i < 64 * (K / 4); i += 256) {
        int r = i / (K / 4);
        int kq = (i % (K / 4)) * 4;
        int gr = rbase + r;
        float4 v = make_float4(0.f, 0.f, 0.f, 0.f);
        if (gr < NN) {
            v = *(const float4*)&X[(size_t)gr * K + kq];
            if (XFORM) {
                float* vc = (float*)&v;
#pragma unroll
                for (int c = 0; c < 4; ++c) {
                    float val = vc[c] * bnsc[kq + c] + bnsc[64 + kq + c];
                    val = val >= 0.f ? val : 0.01f * val;
                    int idx = gr * 64 + kq + c;
                    jkmax[idx] = fmaxf(jkmax[idx], val);
                    vc[c] = val;
                }
            }
        }
        uint2 u;
        u.x = (unsigned int)f2bf(v.x) | ((unsigned int)f2bf(v.y) << 16);
        u.y = (unsigned int)f2bf(v.z) | ((unsigned int)f2bf(v.w) << 16);
        *(uint2*)&As[r * KP + kq] = u;
    }
    for (int i = t; i < 128 * (K / 8); i += 256) {
        int oc = i / (K / 8);
        int k8 = (i % (K / 8)) * 8;
        uint4 v = *(const uint4*)&Wtg[(size_t)oc * K + k8];
        *(uint4*)&Bs[oc * KP + k8] = v;
    }
    __syncthreads();

    int lane = t & 63, wv = t >> 6;
    int lr = lane & 15, quad = lane >> 4;
    int arow = wv * 16 + lr;
    f32x4 acc[8];
#pragma unroll
    for (int c = 0; c < 8; ++c) acc[c] = (f32x4)(0.f);
#pragma unroll
    for (int k0 = 0; k0 < K; k0 += 32) {
        s16x8 a = *(const s16x8*)&As[arow * KP + k0 + quad * 8];
#pragma unroll
        for (int ct = 0; ct < 8; ++ct) {
            s16x8 b = *(const s16x8*)&Bs[(ct * 16 + lr) * KP + k0 + quad * 8];
            acc[ct] = __builtin_amdgcn_mfma_f32_16x16x32_bf16(a, b, acc[ct], 0, 0, 0);
        }
    }

    bool hblock = (!L0) || (blockIdx.y == 0);
#pragma unroll
    for (int reg = 0; reg < 4; ++reg) {
        int row = rbase + wv * 16 + quad * 4 + reg;
        if (hblock) {
            if (row < NN) {
#pragma unroll
                for (int ct = 0; ct < 4; ++ct) {
                    unsigned int pk = (unsigned int)f2bf(acc[ct][reg]) |
                                      ((unsigned int)f2bf(acc[ct + 4][reg]) << 16);
                    Hpk[(size_t)row * 64 + ct * 16 + lr] = pk;
                }
            }
            float s0 = 0.f, s1 = 0.f, d0 = 0.f, d1 = 0.f;
#pragma unroll
            for (int ct = 0; ct < 4; ++ct) {
                int c = ct * 16 + lr;
                float hlo = acc[ct][reg], hhi = acc[ct + 4][reg];
                s0 += hlo * as_v[c];
                s1 += hhi * as_v[64 + c];
                d0 += hlo * ad_v[c];
                d1 += hhi * ad_v[64 + c];
            }
#pragma unroll
            for (int off = 1; off < 16; off <<= 1) {
                s0 += __shfl_xor(s0, off, 64);
                s1 += __shfl_xor(s1, off, 64);
                d0 += __shfl_xor(d0, off, 64);
                d1 += __shfl_xor(d1, off, 64);
            }
            if (lr == 0 && row < NN) {
                e_srcpk[row] = (unsigned int)f2bf(s0) | ((unsigned int)f2bf(s1) << 16);
                e_dstpk[row] = (unsigned int)f2bf(d0) | ((unsigned int)f2bf(d1) << 16);
            }
        } else if (row < NN) {
#pragma unroll
            for (int ct = 0; ct < 4; ++ct)
                skipx[(size_t)row * 64 + ct * 16 + lr] = acc[ct][reg];
#pragma unroll
            for (int ct = 4; ct < 8; ++ct) {
                int c = (ct - 4) * 16 + lr;
                jkproj[(size_t)row * 64 + c] = acc[ct][reg] + projb[c];
            }
        }
    }
}

// Per-edge unnormalized softmax weights in CSR order. Coalesced csr reads;
// e_dstpk gathers are monotone (CSR is dst-sorted) -> L1 stream; e_srcpk
// random but table is 400KB (L2-resident). One exp per edge per head, once.
__global__ void edge_w(const int* __restrict__ csr_src, const int* __restrict__ csr_dst,
                       const unsigned int* __restrict__ e_srcpk,
                       const unsigned int* __restrict__ e_dstpk,
                       unsigned int* __restrict__ walpha) {
    int i = blockIdx.x * blockDim.x + threadIdx.x;
    if (i >= NE) return;
    unsigned int q = e_srcpk[csr_src[i]];
    unsigned int r = e_dstpk[csr_dst[i]];
    float a0 = bf_lo(q) + bf_lo(r);
    float a1 = bf_hi(q) + bf_hi(r);
    a0 = a0 >= 0.f ? a0 : 0.2f * a0;
    a1 = a1 >= 0.f ? a1 : 0.2f * a1;
    walpha[i] = (unsigned int)f2bf(__expf(a0)) | ((unsigned int)f2bf(__expf(a1)) << 16);
}

// One wave per destination node. Per edge: uniform csr_src + uniform walpha
// + one 4B packed-bf16 h gather per lane; ~8 VALU ops/edge. 4x unroll for
// four outstanding gather chains.
__global__ __launch_bounds__(256) void aggregate(
    const int* __restrict__ offsets, const int* __restrict__ csr_src,
    const unsigned int* __restrict__ walpha, const unsigned int* __restrict__ Hpk,
    const float* __restrict__ skipsrc, const float* __restrict__ bnsc,
    const float* __restrict__ bias, float* __restrict__ hraw) {
    int wave = threadIdx.x >> 6;
    int lane = threadIdx.x & 63;
    int n = blockIdx.x * 4 + wave;
    if (n >= NN) return;
    int beg = offsets[n], end = offsets[n + 1];
    float acc0 = 0.f, acc1 = 0.f, den0 = 0.f, den1 = 0.f;
    int j = beg;
    for (; j + 3 < end; j += 4) {
        int s0 = csr_src[j], s1 = csr_src[j + 1], s2 = csr_src[j + 2], s3 = csr_src[j + 3];
        unsigned int w0 = walpha[j], w1 = walpha[j + 1], w2 = walpha[j + 2],
                     w3 = walpha[j + 3];
        unsigned int p0 = Hpk[(size_t)s0 * 64 + lane];
        unsigned int p1 = Hpk[(size_t)s1 * 64 + lane];
        unsigned int p2 = Hpk[(size_t)s2 * 64 + lane];
        unsigned int p3 = Hpk[(size_t)s3 * 64 + lane];
        den0 += bf_lo(w0) + bf_lo(w1) + bf_lo(w2) + bf_lo(w3);
        den1 += bf_hi(w0) + bf_hi(w1) + bf_hi(w2) + bf_hi(w3);
        acc0 += bf_lo(w0) * bf_lo(p0) + bf_lo(w1) * bf_lo(p1) + bf_lo(w2) * bf_lo(p2) +
                bf_lo(w3) * bf_lo(p3);
        acc1 += bf_hi(w0) * bf_hi(p0) + bf_hi(w1) * bf_hi(p1) + bf_hi(w2) * bf_hi(p2) +
                bf_hi(w3) * bf_hi(p3);
    }
    for (; j < end; ++j) {
        int s0 = csr_src[j];
        unsigned int w0 = walpha[j];
        unsigned int p0 = Hpk[(size_t)s0 * 64 + lane];
        den0 += bf_lo(w0);
        den1 += bf_hi(w0);
        acc0 += bf_lo(w0) * bf_lo(p0);
        acc1 += bf_hi(w0) * bf_hi(p0);
    }
    float sv = skipsrc[(size_t)n * 64 + lane];
    if (bnsc) {  // identity skip from previous layer's pre-BN buffer
        sv = sv * bnsc[lane] + bnsc[64 + lane];
        sv = sv >= 0.f ? sv : 0.01f * sv;
    }
    float o = 0.5f * (acc0 / (den0 + 1e-16f) + acc1 / (den1 + 1e-16f)) + bias[lane] + sv;
    hraw[(size_t)n * 64 + lane] = o;
}

__global__ void bn_stats(const float* __restrict__ x, float* __restrict__ sums) {
    __shared__ float ls[256], ls2[256];
    int t = threadIdx.x;
    int c = t & 63, q = t >> 6;
    float s = 0.f, s2 = 0.f;
    int rbeg = blockIdx.x * 512;
    for (int r = rbeg + q; r < rbeg + 512; r += 4) {
        if (r < NN) {
            float v = x[(size_t)r * 64 + c];
            s += v;
            s2 += v * v;
        }
    }
    ls[t] = s;
    ls2[t] = s2;
    __syncthreads();
    if (t < 64) {
        s = ls[t] + ls[t + 64] + ls[t + 128] + ls[t + 192];
        s2 = ls2[t] + ls2[t + 64] + ls2[t + 128] + ls2[t + 192];
        atomicAdd(&sums[c], s);
        atomicAdd(&sums[64 + c], s2);
    }
}

__global__ void bn_final(const float* __restrict__ sums, const float* __restrict__ g,
                         const float* __restrict__ be, float* __restrict__ sc_sh) {
    int c = threadIdx.x;
    if (c < 64) {
        float mu = sums[c] / (float)NN;
        float var = sums[64 + c] / (float)NN - mu * mu;
        float sc = g[c] * rsqrtf(var + 1e-5f);
        sc_sh[c] = sc;
        sc_sh[64 + c] = be[c] - mu * sc;
    }
}

__global__ void final_out(const float* __restrict__ hraw, const float* __restrict__ sc_sh,
                          const float* __restrict__ jk, float* __restrict__ out) {
    int i = blockIdx.x * blockDim.x + threadIdx.x;
    if (i < NN * 64) {
        int c = i & 63;
        float v = hraw[i] * sc_sh[c] + sc_sh[64 + c];
        v = v >= 0.f ? v : 0.01f * v;
        out[i] = fmaxf(jk[i], v);
    }
}

extern "C" void kernel_launch(void* const* d_in, const int* in_sizes, int n_in,
                              void* d_out, int out_size, void* d_ws, size_t ws_size,
                              hipStream_t stream) {
    const float* x = (const float*)d_in[0];
    const int* ei = (const int*)d_in[1];
    const int* e_src_idx = ei;
    const int* e_dst_idx = ei + NE;
    const float* W0 = (const float*)d_in[2];
    const float* as0 = (const float*)d_in[3];
    const float* ad0 = (const float*)d_in[4];
    const float* b0 = (const float*)d_in[5];
    const float* skip0 = (const float*)d_in[6];
    const float* g0 = (const float*)d_in[7];
    const float* be0 = (const float*)d_in[8];
    const float* W1 = (const float*)d_in[9];
    const float* as1 = (const float*)d_in[10];
    const float* ad1 = (const float*)d_in[11];
    const float* b1 = (const float*)d_in[12];
    const float* g1 = (const float*)d_in[13];
    const float* be1 = (const float*)d_in[14];
    const float* W2 = (const float*)d_in[15];
    const float* as2 = (const float*)d_in[16];
    const float* ad2 = (const float*)d_in[17];
    const float* b2 = (const float*)d_in[18];
    const float* g2 = (const float*)d_in[19];
    const float* be2 = (const float*)d_in[20];
    const float* projW = (const float*)d_in[21];
    const float* projb = (const float*)d_in[22];
    float* out = (float*)d_out;

    char* p = (char*)d_ws;
    auto alloc = [&](size_t bytes) {
        char* r = p;
        p += (bytes + 255) & ~(size_t)255;
        return r;
    };
    int* deg = (int*)alloc((size_t)NN * 4);  // reused as scatter cursor
    int* offsets = (int*)alloc((size_t)(NN + 1) * 4);
    int* partial = (int*)alloc((size_t)NB_SCAN * 4);
    int* bucket_cursor = (int*)alloc((size_t)NBUC * 4);
    int* csr_src = (int*)alloc((size_t)NE * 4);
    int* csr_dst = (int*)alloc((size_t)NE * 4);
    unsigned int* walpha = (unsigned int*)alloc((size_t)NE * 4);
    uint2* binned = (uint2*)alloc((size_t)NE * 8);
    unsigned int* h_pk = (unsigned int*)alloc((size_t)NN * 64 * 4);
    unsigned int* e_srcpk = (unsigned int*)alloc((size_t)NN * 4);
    unsigned int* e_dstpk = (unsigned int*)alloc((size_t)NN * 4);
    float* skipx = (float*)alloc((size_t)NN * 64 * 4);
    float* jk = (float*)alloc((size_t)NN * 64 * 4);
    float* hrawA = (float*)alloc((size_t)NN * 64 * 4);
    float* hrawB = (float*)alloc((size_t)NN * 64 * 4);
    unsigned short* Wtcat = (unsigned short*)alloc(256 * 128 * 2);
    unsigned short* Wt1 = (unsigned short*)alloc(128 * 64 * 2);
    unsigned short* Wt2 = (unsigned short*)alloc(128 * 64 * 2);
    float* bnsumAll = (float*)alloc(3 * 128 * 4);
    float* bnsc = (float*)alloc(128 * 4);
    if ((size_t)(p - (char*)d_ws) > ws_size) return;

    // ---- CSR by destination (binned two-pass) + weight prep ----
    zero_u32<<<(NN + 255) / 256, 256, 0, stream>>>((unsigned int*)deg, NN);
    zero_u32<<<2, 256, 0, stream>>>((unsigned int*)bnsumAll, 3 * 128);
    count_deg<<<(NE + 255) / 256, 256, 0, stream>>>(e_dst_idx, deg);
    scan_partial<<<NB_SCAN, 256, 0, stream>>>(deg, partial);
    scan_serial<<<1, 64, 0, stream>>>(partial, offsets);
    scan_final<<<NB_SCAN, 256, 0, stream>>>(deg, partial, offsets, deg);
    bucket_init<<<1, 256, 0, stream>>>(offsets, bucket_cursor);
    bin_edges<<<NB_BIN, 256, 0, stream>>>(e_src_idx, e_dst_idx, bucket_cursor, binned);
    scatter_local<<<(NE + 255) / 256, 256, 0, stream>>>(binned, deg, csr_src, csr_dst);
    prep_weights<<<192, 256, 0, stream>>>(W0, skip0, projW, W1, W2, Wtcat, Wt1, Wt2);

    int gblocks = (NN + 63) / 64;  // 1563

    // ---- Layer 0 (one GEMM: h+scores | skip+proj) ----
    gemm_mfma<128, true, false><<<dim3(gblocks, 2), 256, 0, stream>>>(
        x, Wtcat, h_pk, skipx, jk, projb, nullptr, nullptr, as0, ad0, e_srcpk, e_dstpk);
    edge_w<<<(NE + 255) / 256, 256, 0, stream>>>(csr_src, csr_dst, e_srcpk, e_dstpk, walpha);
    aggregate<<<(NN + 3) / 4, 256, 0, stream>>>(offsets, csr_src, walpha, h_pk,
                                                skipx, nullptr, b0, hrawA);
    bn_stats<<<(NN + 511) / 512, 256, 0, stream>>>(hrawA, bnsumAll);
    bn_final<<<1, 64, 0, stream>>>(bnsumAll, g0, be0, bnsc);

    // ---- Layer 1 ----
    gemm_mfma<64, false, true><<<dim3(gblocks, 1), 256, 0, stream>>>(
        hrawA, Wt1, h_pk, nullptr, nullptr, nullptr, bnsc, jk, as1, ad1, e_srcpk, e_dstpk);
    edge_w<<<(NE + 255) / 256, 256, 0, stream>>>(csr_src, csr_dst, e_srcpk, e_dstpk, walpha);
    aggregate<<<(NN + 3) / 4, 256, 0, stream>>>(offsets, csr_src, walpha, h_pk,
                                                hrawA, bnsc, b1, hrawB);
    bn_stats<<<(NN + 511) / 512, 256, 0, stream>>>(hrawB, bnsumAll + 128);
    bn_final<<<1, 64, 0, stream>>>(bnsumAll + 128, g1, be1, bnsc);

    // ---- Layer 2 ----
    gemm_mfma<64, false, true><<<dim3(gblocks, 1), 256, 0, stream>>>(
        hrawB, Wt2, h_pk, nullptr, nullptr, nullptr, bnsc, jk, as2, ad2, e_srcpk, e_dstpk);
    edge_w<<<(NE + 255) / 256, 256, 0, stream>>>(csr_src, csr_dst, e_srcpk, e_dstpk, walpha);
    aggregate<<<(NN + 3) / 4, 256, 0, stream>>>(offsets, csr_src, walpha, h_pk,
                                                hrawB, bnsc, b2, hrawA);
    bn_stats<<<(NN + 511) / 512, 256, 0, stream>>>(hrawA, bnsumAll + 256);
    bn_final<<<1, 64, 0, stream>>>(bnsumAll + 256, g2, be2, bnsc);

    final_out<<<(NN * 64 + 255) / 256, 256, 0, stream>>>(hrawA, bnsc, jk, out);
}

// Round 7
// 676.809 us; speedup vs baseline: 2.2179x; 1.1321x over previous
//
#include <hip/hip_runtime.h>

#define NN 100000
#define NE 1600000

constexpr int NBUC = 196;       // bucket = dst >> 9 (512 nodes/bucket)
constexpr int BIN_CHUNK = 4096;
constexpr int NB_BIN = (NE + BIN_CHUNK - 1) / BIN_CHUNK;  // 391

typedef __attribute__((ext_vector_type(8))) short s16x8;
typedef __attribute__((ext_vector_type(4))) float f32x4;
typedef __attribute__((ext_vector_type(2))) float f32x2;

__device__ inline unsigned short f2bf(float f) {  // RNE fp32 -> bf16 bits
    unsigned int u = __float_as_uint(f);
    return (unsigned short)((u + 0x7fffu + ((u >> 16) & 1u)) >> 16);
}
__device__ inline float bf_lo(unsigned int pk) { return __uint_as_float(pk << 16); }
__device__ inline float bf_hi(unsigned int pk) { return __uint_as_float(pk & 0xffff0000u); }

__global__ void zero_u32(unsigned int* p, int n) {
    int i = blockIdx.x * blockDim.x + threadIdx.x;
    if (i < n) p[i] = 0u;
}

// Histogram of dst buckets (LDS-combined, 196 global atomics per block).
__global__ __launch_bounds__(256) void bucket_count(const int* __restrict__ dst,
                                                    int* __restrict__ bcount) {
    __shared__ int hist[NBUC];
    int t = threadIdx.x;
    for (int b = t; b < NBUC; b += 256) hist[b] = 0;
    __syncthreads();
    int beg = blockIdx.x * BIN_CHUNK;
    int end = min(beg + BIN_CHUNK, NE);
    for (int i = beg + t; i < end; i += 256) atomicAdd(&hist[dst[i] >> 9], 1);
    __syncthreads();
    for (int b = t; b < NBUC; b += 256)
        if (hist[b]) atomicAdd(&bcount[b], hist[b]);
}

// Serial 196-entry exclusive scan; writes bucket bases + bin cursors.
__global__ void bucket_scan(const int* __restrict__ bcount, int* __restrict__ bbase,
                            int* __restrict__ bucket_cursor, int* __restrict__ offsets) {
    if (threadIdx.x == 0) {
        int run = 0;
        for (int b = 0; b < NBUC; ++b) {
            bbase[b] = run;
            bucket_cursor[b] = run;
            run += bcount[b];
        }
        bbase[NBUC] = NE;
        offsets[NN] = NE;
    }
}

// Bucket-major (src,dst) intermediate: per-block LDS histogram, per-bucket
// chunk reservation (one global atomic per block-bucket), contiguous writes.
__global__ __launch_bounds__(256) void bin_edges(const int* __restrict__ src,
                                                 const int* __restrict__ dst,
                                                 int* __restrict__ bucket_cursor,
                                                 uint2* __restrict__ binned) {
    __shared__ int hist[NBUC];
    __shared__ int base[NBUC];
    int t = threadIdx.x;
    for (int b = t; b < NBUC; b += 256) hist[b] = 0;
    __syncthreads();
    int beg = blockIdx.x * BIN_CHUNK;
    int end = min(beg + BIN_CHUNK, NE);
    for (int i = beg + t; i < end; i += 256) atomicAdd(&hist[dst[i] >> 9], 1);
    __syncthreads();
    for (int b = t; b < NBUC; b += 256) {
        base[b] = hist[b] ? atomicAdd(&bucket_cursor[b], hist[b]) : 0;
        hist[b] = 0;
    }
    __syncthreads();
    for (int i = beg + t; i < end; i += 256) {
        int d = dst[i];
        int bk = d >> 9;
        int loc = atomicAdd(&hist[bk], 1);
        binned[base[bk] + loc] = make_uint2((unsigned)src[i], (unsigned)d);
    }
}

// One block per bucket: LDS counting sort over the bucket's 512 nodes.
// Emits offsets + csr_src/csr_dst with sequential (in-bucket) global writes;
// all fine-grained atomics are LDS.
__global__ __launch_bounds__(256) void bucket_sort(const uint2* __restrict__ binned,
                                                   const int* __restrict__ bbase,
                                                   int* __restrict__ offsets,
                                                   int* __restrict__ csr_src,
                                                   int* __restrict__ csr_dst) {
    __shared__ int deg[512];
    __shared__ int loc[512];
    __shared__ int s2[256];
    int t = threadIdx.x;
    int b = blockIdx.x;
    int beg = bbase[b], end = bbase[b + 1];
    int nbase = b << 9;
    deg[t] = 0;
    deg[t + 256] = 0;
    __syncthreads();
    for (int i = beg + t; i < end; i += 256) atomicAdd(&deg[(int)binned[i].y - nbase], 1);
    __syncthreads();
    int pairsum = deg[2 * t] + deg[2 * t + 1];
    s2[t] = pairsum;
    __syncthreads();
    for (int off = 1; off < 256; off <<= 1) {
        int v = (t >= off) ? s2[t - off] : 0;
        __syncthreads();
        s2[t] += v;
        __syncthreads();
    }
    int ex = s2[t] - pairsum;  // exclusive pair base
    loc[2 * t] = ex;
    loc[2 * t + 1] = ex + deg[2 * t];
    __syncthreads();
    for (int i = t; i < 512; i += 256) {
        int node = nbase + i;
        if (node < NN) offsets[node] = beg + loc[i];
    }
    __syncthreads();
    for (int i = beg + t; i < end; i += 256) {
        uint2 e = binned[i];
        int pos = atomicAdd(&loc[(int)e.y - nbase], 1);
        csr_src[beg + pos] = (int)e.x;
        csr_dst[beg + pos] = (int)e.y;
    }
}

// Transpose + fp32->bf16 all weights once per launch.
// Wtcat[256][128]: cols(oc) 0..127 = W0, 128..191 = skip0, 192..255 = projW.
__global__ void prep_weights(const float* __restrict__ W0, const float* __restrict__ skip0,
                             const float* __restrict__ projW, const float* __restrict__ W1,
                             const float* __restrict__ W2, unsigned short* __restrict__ Wtcat,
                             unsigned short* __restrict__ Wt1, unsigned short* __restrict__ Wt2) {
    int i = blockIdx.x * 256 + threadIdx.x;
    if (i < 32768) {
        int oc = i >> 7, k = i & 127;
        float v;
        if (oc < 128) v = W0[k * 128 + oc];
        else if (oc < 192) v = skip0[k * 64 + (oc - 128)];
        else v = projW[k * 64 + (oc - 192)];
        Wtcat[oc * 128 + k] = f2bf(v);
    } else if (i < 40960) {
        int j = i - 32768, oc = j >> 6, k = j & 63;
        Wt1[oc * 64 + k] = f2bf(W1[k * 128 + oc]);
    } else if (i < 49152) {
        int j = i - 40960, oc = j >> 6, k = j & 63;
        Wt2[oc * 64 + k] = f2bf(W2[k * 128 + oc]);
    }
}

// MFMA bf16 GEMM: block = 64 rows x 128 cols, 4 waves (wave = 16 rows).
// X fp32 [N][K] staged to LDS bf16 (XFORM: BN+lrelu on the fly + JK max).
// h is written as packed fp8-e4m3 pairs (head0|head1, 2B/lane) for the
// aggregation gather; attention scores reduced from fp32 accumulators
// (packed bf16x2 e_srcpk/e_dstpk).
// L0: blockIdx.y==0 -> h + scores; y==1 -> skip (fp32) + proj (+bias).
template <int K, bool L0, bool XFORM>
__global__ __launch_bounds__(256) void gemm_mfma(
    const float* __restrict__ X, const unsigned short* __restrict__ Wt,
    unsigned short* __restrict__ Hq, float* __restrict__ skipx, float* __restrict__ jkproj,
    const float* __restrict__ projb, const float* __restrict__ bnsc,
    float* __restrict__ jkmax, const float* __restrict__ as_v,
    const float* __restrict__ ad_v, unsigned int* __restrict__ e_srcpk,
    unsigned int* __restrict__ e_dstpk) {
    constexpr int KP = K + 8;
    __shared__ unsigned short As[64 * KP];
    __shared__ unsigned short Bs[128 * KP];
    int t = threadIdx.x;
    int rbase = blockIdx.x * 64;
    const unsigned short* Wtg = Wt + (size_t)blockIdx.y * 128 * K;

    for (int i = t; i < 64 * (K / 4); i += 256) {
        int r = i / (K / 4);
        int kq = (i % (K / 4)) * 4;
        int gr = rbase + r;
        float4 v = make_float4(0.f, 0.f, 0.f, 0.f);
        if (gr < NN) {
            v = *(const float4*)&X[(size_t)gr * K + kq];
            if (XFORM) {
                float* vc = (float*)&v;
#pragma unroll
                for (int c = 0; c < 4; ++c) {
                    float val = vc[c] * bnsc[kq + c] + bnsc[64 + kq + c];
                    val = val >= 0.f ? val : 0.01f * val;
                    int idx = gr * 64 + kq + c;
                    jkmax[idx] = fmaxf(jkmax[idx], val);
                    vc[c] = val;
                }
            }
        }
        uint2 u;
        u.x = (unsigned int)f2bf(v.x) | ((unsigned int)f2bf(v.y) << 16);
        u.y = (unsigned int)f2bf(v.z) | ((unsigned int)f2bf(v.w) << 16);
        *(uint2*)&As[r * KP + kq] = u;
    }
    for (int i = t; i < 128 * (K / 8); i += 256) {
        int oc = i / (K / 8);
        int k8 = (i % (K / 8)) * 8;
        uint4 v = *(const uint4*)&Wtg[(size_t)oc * K + k8];
        *(uint4*)&Bs[oc * KP + k8] = v;
    }
    __syncthreads();

    int lane = t & 63, wv = t >> 6;
    int lr = lane & 15, quad = lane >> 4;
    int arow = wv * 16 + lr;
    f32x4 acc[8];
#pragma unroll
    for (int c = 0; c < 8; ++c) acc[c] = (f32x4)(0.f);
#pragma unroll
    for (int k0 = 0; k0 < K; k0 += 32) {
        s16x8 a = *(const s16x8*)&As[arow * KP + k0 + quad * 8];
#pragma unroll
        for (int ct = 0; ct < 8; ++ct) {
            s16x8 b = *(const s16x8*)&Bs[(ct * 16 + lr) * KP + k0 + quad * 8];
            acc[ct] = __builtin_amdgcn_mfma_f32_16x16x32_bf16(a, b, acc[ct], 0, 0, 0);
        }
    }

    bool hblock = (!L0) || (blockIdx.y == 0);
#pragma unroll
    for (int reg = 0; reg < 4; ++reg) {
        int row = rbase + wv * 16 + quad * 4 + reg;
        if (hblock) {
            if (row < NN) {
#pragma unroll
                for (int ct = 0; ct < 4; ++ct) {
                    int pk8 = __builtin_amdgcn_cvt_pk_fp8_f32(acc[ct][reg], acc[ct + 4][reg],
                                                              0, false);
                    Hq[(size_t)row * 64 + ct * 16 + lr] = (unsigned short)pk8;
                }
            }
            float s0 = 0.f, s1 = 0.f, d0 = 0.f, d1 = 0.f;
#pragma unroll
            for (int ct = 0; ct < 4; ++ct) {
                int c = ct * 16 + lr;
                float hlo = acc[ct][reg], hhi = acc[ct + 4][reg];
                s0 += hlo * as_v[c];
                s1 += hhi * as_v[64 + c];
                d0 += hlo * ad_v[c];
                d1 += hhi * ad_v[64 + c];
            }
#pragma unroll
            for (int off = 1; off < 16; off <<= 1) {
                s0 += __shfl_xor(s0, off, 64);
                s1 += __shfl_xor(s1, off, 64);
                d0 += __shfl_xor(d0, off, 64);
                d1 += __shfl_xor(d1, off, 64);
            }
            if (lr == 0 && row < NN) {
                e_srcpk[row] = (unsigned int)f2bf(s0) | ((unsigned int)f2bf(s1) << 16);
                e_dstpk[row] = (unsigned int)f2bf(d0) | ((unsigned int)f2bf(d1) << 16);
            }
        } else if (row < NN) {
#pragma unroll
            for (int ct = 0; ct < 4; ++ct)
                skipx[(size_t)row * 64 + ct * 16 + lr] = acc[ct][reg];
#pragma unroll
            for (int ct = 4; ct < 8; ++ct) {
                int c = (ct - 4) * 16 + lr;
                jkproj[(size_t)row * 64 + c] = acc[ct][reg] + projb[c];
            }
        }
    }
}

// Per-edge unnormalized softmax weights in CSR order (coalesced; dst gathers
// monotone, src gathers hit the 400KB L2-resident score table).
__global__ void edge_w(const int* __restrict__ csr_src, const int* __restrict__ csr_dst,
                       const unsigned int* __restrict__ e_srcpk,
                       const unsigned int* __restrict__ e_dstpk,
                       unsigned int* __restrict__ walpha) {
    int i = blockIdx.x * blockDim.x + threadIdx.x;
    if (i >= NE) return;
    unsigned int q = e_srcpk[csr_src[i]];
    unsigned int r = e_dstpk[csr_dst[i]];
    float a0 = bf_lo(q) + bf_lo(r);
    float a1 = bf_hi(q) + bf_hi(r);
    a0 = a0 >= 0.f ? a0 : 0.2f * a0;
    a1 = a1 >= 0.f ? a1 : 0.2f * a1;
    walpha[i] = (unsigned int)f2bf(__expf(a0)) | ((unsigned int)f2bf(__expf(a1)) << 16);
}

// One wave per destination node. Per edge: uniform csr_src + uniform walpha
// + one 2B fp8-pair gather per lane (v_cvt_pk_f32_fp8 unpack). 4x unroll for
// four outstanding gather chains.
__global__ __launch_bounds__(256) void aggregate(
    const int* __restrict__ offsets, const int* __restrict__ csr_src,
    const unsigned int* __restrict__ walpha, const unsigned short* __restrict__ Hq,
    const float* __restrict__ skipsrc, const float* __restrict__ bnsc,
    const float* __restrict__ bias, float* __restrict__ hraw) {
    int wave = threadIdx.x >> 6;
    int lane = threadIdx.x & 63;
    int n = blockIdx.x * 4 + wave;
    if (n >= NN) return;
    int beg = offsets[n], end = offsets[n + 1];
    float acc0 = 0.f, acc1 = 0.f, den0 = 0.f, den1 = 0.f;
    int j = beg;
    for (; j + 3 < end; j += 4) {
        int s0 = csr_src[j], s1 = csr_src[j + 1], s2 = csr_src[j + 2], s3 = csr_src[j + 3];
        unsigned int w0 = walpha[j], w1 = walpha[j + 1], w2 = walpha[j + 2],
                     w3 = walpha[j + 3];
        int p0 = Hq[(size_t)s0 * 64 + lane];
        int p1 = Hq[(size_t)s1 * 64 + lane];
        int p2 = Hq[(size_t)s2 * 64 + lane];
        int p3 = Hq[(size_t)s3 * 64 + lane];
        f32x2 h0 = __builtin_amdgcn_cvt_pk_f32_fp8(p0, false);
        f32x2 h1 = __builtin_amdgcn_cvt_pk_f32_fp8(p1, false);
        f32x2 h2 = __builtin_amdgcn_cvt_pk_f32_fp8(p2, false);
        f32x2 h3 = __builtin_amdgcn_cvt_pk_f32_fp8(p3, false);
        den0 += bf_lo(w0) + bf_lo(w1) + bf_lo(w2) + bf_lo(w3);
        den1 += bf_hi(w0) + bf_hi(w1) + bf_hi(w2) + bf_hi(w3);
        acc0 += bf_lo(w0) * h0[0] + bf_lo(w1) * h1[0] + bf_lo(w2) * h2[0] + bf_lo(w3) * h3[0];
        acc1 += bf_hi(w0) * h0[1] + bf_hi(w1) * h1[1] + bf_hi(w2) * h2[1] + bf_hi(w3) * h3[1];
    }
    for (; j < end; ++j) {
        int s0 = csr_src[j];
        unsigned int w0 = walpha[j];
        int p0 = Hq[(size_t)s0 * 64 + lane];
        f32x2 h0 = __builtin_amdgcn_cvt_pk_f32_fp8(p0, false);
        den0 += bf_lo(w0);
        den1 += bf_hi(w0);
        acc0 += bf_lo(w0) * h0[0];
        acc1 += bf_hi(w0) * h0[1];
    }
    float sv = skipsrc[(size_t)n * 64 + lane];
    if (bnsc) {  // identity skip from previous layer's pre-BN buffer
        sv = sv * bnsc[lane] + bnsc[64 + lane];
        sv = sv >= 0.f ? sv : 0.01f * sv;
    }
    float o = 0.5f * (acc0 / (den0 + 1e-16f) + acc1 / (den1 + 1e-16f)) + bias[lane] + sv;
    hraw[(size_t)n * 64 + lane] = o;
}

__global__ void bn_stats(const float* __restrict__ x, float* __restrict__ sums) {
    __shared__ float ls[256], ls2[256];
    int t = threadIdx.x;
    int c = t & 63, q = t >> 6;
    float s = 0.f, s2 = 0.f;
    int rbeg = blockIdx.x * 512;
    for (int r = rbeg + q; r < rbeg + 512; r += 4) {
        if (r < NN) {
            float v = x[(size_t)r * 64 + c];
            s += v;
            s2 += v * v;
        }
    }
    ls[t] = s;
    ls2[t] = s2;
    __syncthreads();
    if (t < 64) {
        s = ls[t] + ls[t + 64] + ls[t + 128] + ls[t + 192];
        s2 = ls2[t] + ls2[t + 64] + ls2[t + 128] + ls2[t + 192];
        atomicAdd(&sums[c], s);
        atomicAdd(&sums[64 + c], s2);
    }
}

__global__ void bn_final(const float* __restrict__ sums, const float* __restrict__ g,
                         const float* __restrict__ be, float* __restrict__ sc_sh) {
    int c = threadIdx.x;
    if (c < 64) {
        float mu = sums[c] / (float)NN;
        float var = sums[64 + c] / (float)NN - mu * mu;
        float sc = g[c] * rsqrtf(var + 1e-5f);
        sc_sh[c] = sc;
        sc_sh[64 + c] = be[c] - mu * sc;
    }
}

__global__ void final_out(const float* __restrict__ hraw, const float* __restrict__ sc_sh,
                          const float* __restrict__ jk, float* __restrict__ out) {
    int i = blockIdx.x * blockDim.x + threadIdx.x;
    if (i < NN * 64) {
        int c = i & 63;
        float v = hraw[i] * sc_sh[c] + sc_sh[64 + c];
        v = v >= 0.f ? v : 0.01f * v;
        out[i] = fmaxf(jk[i], v);
    }
}

extern "C" void kernel_launch(void* const* d_in, const int* in_sizes, int n_in,
                              void* d_out, int out_size, void* d_ws, size_t ws_size,
                              hipStream_t stream) {
    const float* x = (const float*)d_in[0];
    const int* ei = (const int*)d_in[1];
    const int* e_src_idx = ei;
    const int* e_dst_idx = ei + NE;
    const float* W0 = (const float*)d_in[2];
    const float* as0 = (const float*)d_in[3];
    const float* ad0 = (const float*)d_in[4];
    const float* b0 = (const float*)d_in[5];
    const float* skip0 = (const float*)d_in[6];
    const float* g0 = (const float*)d_in[7];
    const float* be0 = (const float*)d_in[8];
    const float* W1 = (const float*)d_in[9];
    const float* as1 = (const float*)d_in[10];
    const float* ad1 = (const float*)d_in[11];
    const float* b1 = (const float*)d_in[12];
    const float* g1 = (const float*)d_in[13];
    const float* be1 = (const float*)d_in[14];
    const float* W2 = (const float*)d_in[15];
    const float* as2 = (const float*)d_in[16];
    const float* ad2 = (const float*)d_in[17];
    const float* b2 = (const float*)d_in[18];
    const float* g2 = (const float*)d_in[19];
    const float* be2 = (const float*)d_in[20];
    const float* projW = (const float*)d_in[21];
    const float* projb = (const float*)d_in[22];
    float* out = (float*)d_out;

    char* p = (char*)d_ws;
    auto alloc = [&](size_t bytes) {
        char* r = p;
        p += (bytes + 255) & ~(size_t)255;
        return r;
    };
    // bcount (196 ints) + bnsumAll (384 floats) share one zeroed buffer.
    int* zbuf = (int*)alloc((size_t)(196 + 384) * 4);
    int* bcount = zbuf;
    float* bnsumAll = (float*)(zbuf + 196);
    int* bbase = (int*)alloc((size_t)(NBUC + 1) * 4);
    int* bucket_cursor = (int*)alloc((size_t)NBUC * 4);
    int* offsets = (int*)alloc((size_t)(NN + 1) * 4);
    int* csr_src = (int*)alloc((size_t)NE * 4);
    int* csr_dst = (int*)alloc((size_t)NE * 4);
    unsigned int* walpha = (unsigned int*)alloc((size_t)NE * 4);
    uint2* binned = (uint2*)alloc((size_t)NE * 8);
    unsigned short* h_q = (unsigned short*)alloc((size_t)NN * 64 * 2);
    unsigned int* e_srcpk = (unsigned int*)alloc((size_t)NN * 4);
    unsigned int* e_dstpk = (unsigned int*)alloc((size_t)NN * 4);
    float* skipx = (float*)alloc((size_t)NN * 64 * 4);
    float* jk = (float*)alloc((size_t)NN * 64 * 4);
    float* hrawA = (float*)alloc((size_t)NN * 64 * 4);
    float* hrawB = (float*)alloc((size_t)NN * 64 * 4);
    unsigned short* Wtcat = (unsigned short*)alloc(256 * 128 * 2);
    unsigned short* Wt1 = (unsigned short*)alloc(128 * 64 * 2);
    unsigned short* Wt2 = (unsigned short*)alloc(128 * 64 * 2);
    float* bnsc = (float*)alloc(128 * 4);
    if ((size_t)(p - (char*)d_ws) > ws_size) return;

    // ---- CSR by destination: bucket count -> scan -> bin -> LDS sort ----
    zero_u32<<<3, 256, 0, stream>>>((unsigned int*)zbuf, 196 + 384);
    bucket_count<<<NB_BIN, 256, 0, stream>>>(e_dst_idx, bcount);
    bucket_scan<<<1, 64, 0, stream>>>(bcount, bbase, bucket_cursor, offsets);
    bin_edges<<<NB_BIN, 256, 0, stream>>>(e_src_idx, e_dst_idx, bucket_cursor, binned);
    bucket_sort<<<NBUC, 256, 0, stream>>>(binned, bbase, offsets, csr_src, csr_dst);
    prep_weights<<<192, 256, 0, stream>>>(W0, skip0, projW, W1, W2, Wtcat, Wt1, Wt2);

    int gblocks = (NN + 63) / 64;  // 1563

    // ---- Layer 0 (one GEMM: h+scores | skip+proj) ----
    gemm_mfma<128, true, false><<<dim3(gblocks, 2), 256, 0, stream>>>(
        x, Wtcat, h_q, skipx, jk, projb, nullptr, nullptr, as0, ad0, e_srcpk, e_dstpk);
    edge_w<<<(NE + 255) / 256, 256, 0, stream>>>(csr_src, csr_dst, e_srcpk, e_dstpk, walpha);
    aggregate<<<(NN + 3) / 4, 256, 0, stream>>>(offsets, csr_src, walpha, h_q,
                                                skipx, nullptr, b0, hrawA);
    bn_stats<<<(NN + 511) / 512, 256, 0, stream>>>(hrawA, bnsumAll);
    bn_final<<<1, 64, 0, stream>>>(bnsumAll, g0, be0, bnsc);

    // ---- Layer 1 ----
    gemm_mfma<64, false, true><<<dim3(gblocks, 1), 256, 0, stream>>>(
        hrawA, Wt1, h_q, nullptr, nullptr, nullptr, bnsc, jk, as1, ad1, e_srcpk, e_dstpk);
    edge_w<<<(NE + 255) / 256, 256, 0, stream>>>(csr_src, csr_dst, e_srcpk, e_dstpk, walpha);
    aggregate<<<(NN + 3) / 4, 256, 0, stream>>>(offsets, csr_src, walpha, h_q,
                                                hrawA, bnsc, b1, hrawB);
    bn_stats<<<(NN + 511) / 512, 256, 0, stream>>>(hrawB, bnsumAll + 128);
    bn_final<<<1, 64, 0, stream>>>(bnsumAll + 128, g1, be1, bnsc);

    // ---- Layer 2 ----
    gemm_mfma<64, false, true><<<dim3(gblocks, 1), 256, 0, stream>>>(
        hrawB, Wt2, h_q, nullptr, nullptr, nullptr, bnsc, jk, as2, ad2, e_srcpk, e_dstpk);
    edge_w<<<(NE + 255) / 256, 256, 0, stream>>>(csr_src, csr_dst, e_srcpk, e_dstpk, walpha);
    aggregate<<<(NN + 3) / 4, 256, 0, stream>>>(offsets, csr_src, walpha, h_q,
                                                hrawB, bnsc, b2, hrawA);
    bn_stats<<<(NN + 511) / 512, 256, 0, stream>>>(hrawA, bnsumAll + 256);
    bn_final<<<1, 64, 0, stream>>>(bnsumAll + 256, g2, be2, bnsc);

    final_out<<<(NN * 64 + 255) / 256, 256, 0, stream>>>(hrawA, bnsc, jk, out);
}

// Round 8
// 666.004 us; speedup vs baseline: 2.2539x; 1.0162x over previous
//
#include <hip/hip_runtime.h>

#define NN 100000
#define NE 1600000

constexpr int NBUC = 196;       // bucket = dst >> 9 (512 nodes/bucket)
constexpr int BIN_CHUNK = 4096;
constexpr int NB_BIN = (NE + BIN_CHUNK - 1) / BIN_CHUNK;  // 391

typedef __attribute__((ext_vector_type(8))) short s16x8;
typedef __attribute__((ext_vector_type(4))) float f32x4;
typedef __attribute__((ext_vector_type(2))) float f32x2;

__device__ inline unsigned short f2bf(float f) {  // RNE fp32 -> bf16 bits
    unsigned int u = __float_as_uint(f);
    return (unsigned short)((u + 0x7fffu + ((u >> 16) & 1u)) >> 16);
}
__device__ inline float bf_lo(unsigned int pk) { return __uint_as_float(pk << 16); }
__device__ inline float bf_hi(unsigned int pk) { return __uint_as_float(pk & 0xffff0000u); }

__global__ void zero_u32(unsigned int* p, int n) {
    int i = blockIdx.x * blockDim.x + threadIdx.x;
    if (i < n) p[i] = 0u;
}

// Histogram of dst buckets (LDS-combined, 196 global atomics per block).
__global__ __launch_bounds__(256) void bucket_count(const int* __restrict__ dst,
                                                    int* __restrict__ bcount) {
    __shared__ int hist[NBUC];
    int t = threadIdx.x;
    for (int b = t; b < NBUC; b += 256) hist[b] = 0;
    __syncthreads();
    int beg = blockIdx.x * BIN_CHUNK;
    int end = min(beg + BIN_CHUNK, NE);
    for (int i = beg + t; i < end; i += 256) atomicAdd(&hist[dst[i] >> 9], 1);
    __syncthreads();
    for (int b = t; b < NBUC; b += 256)
        if (hist[b]) atomicAdd(&bcount[b], hist[b]);
}

// Serial 196-entry exclusive scan; writes bucket bases + bin cursors.
__global__ void bucket_scan(const int* __restrict__ bcount, int* __restrict__ bbase,
                            int* __restrict__ bucket_cursor, int* __restrict__ offsets) {
    if (threadIdx.x == 0) {
        int run = 0;
        for (int b = 0; b < NBUC; ++b) {
            bbase[b] = run;
            bucket_cursor[b] = run;
            run += bcount[b];
        }
        bbase[NBUC] = NE;
        offsets[NN] = NE;
    }
}

// Bucket-major packed intermediate: (local_dst9 << 17) | src17. Per-block LDS
// histogram, per-bucket chunk reservation, contiguous 4B writes.
__global__ __launch_bounds__(256) void bin_edges(const int* __restrict__ src,
                                                 const int* __restrict__ dst,
                                                 int* __restrict__ bucket_cursor,
                                                 unsigned int* __restrict__ binned) {
    __shared__ int hist[NBUC];
    __shared__ int base[NBUC];
    int t = threadIdx.x;
    for (int b = t; b < NBUC; b += 256) hist[b] = 0;
    __syncthreads();
    int beg = blockIdx.x * BIN_CHUNK;
    int end = min(beg + BIN_CHUNK, NE);
    for (int i = beg + t; i < end; i += 256) atomicAdd(&hist[dst[i] >> 9], 1);
    __syncthreads();
    for (int b = t; b < NBUC; b += 256) {
        base[b] = hist[b] ? atomicAdd(&bucket_cursor[b], hist[b]) : 0;
        hist[b] = 0;
    }
    __syncthreads();
    for (int i = beg + t; i < end; i += 256) {
        int d = dst[i];
        int bk = d >> 9;
        int loc = atomicAdd(&hist[bk], 1);
        binned[base[bk] + loc] = ((unsigned)(d & 511) << 17) | (unsigned)src[i];
    }
}

// One block per bucket: LDS counting sort over the bucket's 512 nodes.
// Emits offsets + csr_src/csr_dst with sequential (in-bucket) global writes.
__global__ __launch_bounds__(256) void bucket_sort(const unsigned int* __restrict__ binned,
                                                   const int* __restrict__ bbase,
                                                   int* __restrict__ offsets,
                                                   int* __restrict__ csr_src,
                                                   int* __restrict__ csr_dst) {
    __shared__ int deg[512];
    __shared__ int loc[512];
    __shared__ int s2[256];
    int t = threadIdx.x;
    int b = blockIdx.x;
    int beg = bbase[b], end = bbase[b + 1];
    int nbase = b << 9;
    deg[t] = 0;
    deg[t + 256] = 0;
    __syncthreads();
    for (int i = beg + t; i < end; i += 256) atomicAdd(&deg[binned[i] >> 17], 1);
    __syncthreads();
    int pairsum = deg[2 * t] + deg[2 * t + 1];
    s2[t] = pairsum;
    __syncthreads();
    for (int off = 1; off < 256; off <<= 1) {
        int v = (t >= off) ? s2[t - off] : 0;
        __syncthreads();
        s2[t] += v;
        __syncthreads();
    }
    int ex = s2[t] - pairsum;  // exclusive pair base
    loc[2 * t] = ex;
    loc[2 * t + 1] = ex + deg[2 * t];
    __syncthreads();
    for (int i = t; i < 512; i += 256) {
        int node = nbase + i;
        if (node < NN) offsets[node] = beg + loc[i];
    }
    __syncthreads();
    for (int i = beg + t; i < end; i += 256) {
        unsigned int v = binned[i];
        int dl = v >> 17;
        int pos = atomicAdd(&loc[dl], 1);
        csr_src[beg + pos] = (int)(v & 0x1FFFFu);
        csr_dst[beg + pos] = nbase + dl;
    }
}

// Transpose + fp32->bf16 all weights once per launch.
// Wtcat[256][128]: cols(oc) 0..127 = W0, 128..191 = skip0, 192..255 = projW.
__global__ void prep_weights(const float* __restrict__ W0, const float* __restrict__ skip0,
                             const float* __restrict__ projW, const float* __restrict__ W1,
                             const float* __restrict__ W2, unsigned short* __restrict__ Wtcat,
                             unsigned short* __restrict__ Wt1, unsigned short* __restrict__ Wt2) {
    int i = blockIdx.x * 256 + threadIdx.x;
    if (i < 32768) {
        int oc = i >> 7, k = i & 127;
        float v;
        if (oc < 128) v = W0[k * 128 + oc];
        else if (oc < 192) v = skip0[k * 64 + (oc - 128)];
        else v = projW[k * 64 + (oc - 192)];
        Wtcat[oc * 128 + k] = f2bf(v);
    } else if (i < 40960) {
        int j = i - 32768, oc = j >> 6, k = j & 63;
        Wt1[oc * 64 + k] = f2bf(W1[k * 128 + oc]);
    } else if (i < 49152) {
        int j = i - 40960, oc = j >> 6, k = j & 63;
        Wt2[oc * 64 + k] = f2bf(W2[k * 128 + oc]);
    }
}

// MFMA bf16 GEMM: block = 64 rows x 128 cols, 4 waves (wave = 16 rows).
// X fp32 [N][K] staged to LDS bf16 (XFORM: BN+lrelu on the fly).
// h written as [node][32] dwords: dword u = channels (2u,2u+1), each a packed
// fp8-e4m3 (head0,head1) pair -> aggregate gathers one dword per 2 channels.
// Scores reduced from fp32 accumulators (packed bf16x2 e_srcpk/e_dstpk).
// L0: blockIdx.y==0 -> h + scores; y==1 -> skip (fp32) + proj (+bias).
template <int K, bool L0, bool XFORM>
__global__ __launch_bounds__(256) void gemm_mfma(
    const float* __restrict__ X, const unsigned short* __restrict__ Wt,
    unsigned int* __restrict__ Hq32, float* __restrict__ skipx, float* __restrict__ jkproj,
    const float* __restrict__ projb, const float* __restrict__ bnsc,
    const float* __restrict__ as_v, const float* __restrict__ ad_v,
    unsigned int* __restrict__ e_srcpk, unsigned int* __restrict__ e_dstpk) {
    constexpr int KP = K + 8;
    __shared__ unsigned short As[64 * KP];
    __shared__ unsigned short Bs[128 * KP];
    int t = threadIdx.x;
    int rbase = blockIdx.x * 64;
    const unsigned short* Wtg = Wt + (size_t)blockIdx.y * 128 * K;

    for (int i = t; i < 64 * (K / 4); i += 256) {
        int r = i / (K / 4);
        int kq = (i % (K / 4)) * 4;
        int gr = rbase + r;
        float4 v = make_float4(0.f, 0.f, 0.f, 0.f);
        if (gr < NN) {
            v = *(const float4*)&X[(size_t)gr * K + kq];
            if (XFORM) {
                float* vc = (float*)&v;
#pragma unroll
                for (int c = 0; c < 4; ++c) {
                    float val = vc[c] * bnsc[kq + c] + bnsc[64 + kq + c];
                    vc[c] = val >= 0.f ? val : 0.01f * val;
                }
            }
        }
        uint2 u;
        u.x = (unsigned int)f2bf(v.x) | ((unsigned int)f2bf(v.y) << 16);
        u.y = (unsigned int)f2bf(v.z) | ((unsigned int)f2bf(v.w) << 16);
        *(uint2*)&As[r * KP + kq] = u;
    }
    for (int i = t; i < 128 * (K / 8); i += 256) {
        int oc = i / (K / 8);
        int k8 = (i % (K / 8)) * 8;
        uint4 v = *(const uint4*)&Wtg[(size_t)oc * K + k8];
        *(uint4*)&Bs[oc * KP + k8] = v;
    }
    __syncthreads();

    int lane = t & 63, wv = t >> 6;
    int lr = lane & 15, quad = lane >> 4;
    int arow = wv * 16 + lr;
    f32x4 acc[8];
#pragma unroll
    for (int c = 0; c < 8; ++c) acc[c] = (f32x4)(0.f);
#pragma unroll
    for (int k0 = 0; k0 < K; k0 += 32) {
        s16x8 a = *(const s16x8*)&As[arow * KP + k0 + quad * 8];
#pragma unroll
        for (int ct = 0; ct < 8; ++ct) {
            s16x8 b = *(const s16x8*)&Bs[(ct * 16 + lr) * KP + k0 + quad * 8];
            acc[ct] = __builtin_amdgcn_mfma_f32_16x16x32_bf16(a, b, acc[ct], 0, 0, 0);
        }
    }

    bool hblock = (!L0) || (blockIdx.y == 0);
#pragma unroll
    for (int reg = 0; reg < 4; ++reg) {
        int row = rbase + wv * 16 + quad * 4 + reg;
        if (hblock) {
            if (row < NN) {
#pragma unroll
                for (int ct = 0; ct < 4; ++ct) {
                    int pk = __builtin_amdgcn_cvt_pk_fp8_f32(acc[ct][reg], acc[ct + 4][reg],
                                                             0, false);
                    int pn = __shfl_xor(pk, 1, 64);  // partner channel (lr^1)
                    if (!(lr & 1))
                        Hq32[(size_t)row * 32 + ct * 8 + (lr >> 1)] =
                            (unsigned int)((pk & 0xFFFF) | (pn << 16));
                }
            }
            float s0 = 0.f, s1 = 0.f, d0 = 0.f, d1 = 0.f;
#pragma unroll
            for (int ct = 0; ct < 4; ++ct) {
                int c = ct * 16 + lr;
                float hlo = acc[ct][reg], hhi = acc[ct + 4][reg];
                s0 += hlo * as_v[c];
                s1 += hhi * as_v[64 + c];
                d0 += hlo * ad_v[c];
                d1 += hhi * ad_v[64 + c];
            }
#pragma unroll
            for (int off = 1; off < 16; off <<= 1) {
                s0 += __shfl_xor(s0, off, 64);
                s1 += __shfl_xor(s1, off, 64);
                d0 += __shfl_xor(d0, off, 64);
                d1 += __shfl_xor(d1, off, 64);
            }
            if (lr == 0 && row < NN) {
                e_srcpk[row] = (unsigned int)f2bf(s0) | ((unsigned int)f2bf(s1) << 16);
                e_dstpk[row] = (unsigned int)f2bf(d0) | ((unsigned int)f2bf(d1) << 16);
            }
        } else if (row < NN) {
#pragma unroll
            for (int ct = 0; ct < 4; ++ct)
                skipx[(size_t)row * 64 + ct * 16 + lr] = acc[ct][reg];
#pragma unroll
            for (int ct = 4; ct < 8; ++ct) {
                int c = (ct - 4) * 16 + lr;
                jkproj[(size_t)row * 64 + c] = acc[ct][reg] + projb[c];
            }
        }
    }
}

// Per-edge records in CSR order: erec[i] = {src, packed bf16x2 weight}.
__global__ void edge_w(const int* __restrict__ csr_src, const int* __restrict__ csr_dst,
                       const unsigned int* __restrict__ e_srcpk,
                       const unsigned int* __restrict__ e_dstpk,
                       uint2* __restrict__ erec) {
    int i = blockIdx.x * blockDim.x + threadIdx.x;
    if (i >= NE) return;
    int s = csr_src[i];
    unsigned int q = e_srcpk[s];
    unsigned int r = e_dstpk[csr_dst[i]];
    float a0 = bf_lo(q) + bf_lo(r);
    float a1 = bf_hi(q) + bf_hi(r);
    a0 = a0 >= 0.f ? a0 : 0.2f * a0;
    a1 = a1 >= 0.f ? a1 : 0.2f * a1;
    unsigned int w = (unsigned int)f2bf(__expf(a0)) | ((unsigned int)f2bf(__expf(a1)) << 16);
    erec[i] = make_uint2((unsigned)s, w);
}

// One wave per destination node, split in half-waves: lanes 0-31 take even
// edges, 32-63 odd edges; each lane covers 2 channels x 2 heads via one dword
// fp8 gather. Per 2 edges: 2 VMEM + ~12 VALU. Halves merged by shfl at end.
__global__ __launch_bounds__(256) void aggregate(
    const int* __restrict__ offsets, const uint2* __restrict__ erec,
    const unsigned int* __restrict__ Hq32, const float* __restrict__ skipsrc,
    const float* __restrict__ bnsc, const float* __restrict__ bias,
    float* __restrict__ hraw) {
    int wave = threadIdx.x >> 6;
    int lane = threadIdx.x & 63;
    int n = blockIdx.x * 4 + wave;
    if (n >= NN) return;
    int half = lane >> 5;   // which edge of the pair
    int cp = lane & 31;     // channel pair
    int beg = offsets[n], end = offsets[n + 1];
    float a00 = 0.f, a01 = 0.f, a10 = 0.f, a11 = 0.f, den0 = 0.f, den1 = 0.f;
    int j = beg;
    for (; j + 3 < end; j += 4) {
        uint2 eA = erec[j + half];
        uint2 eB = erec[j + 2 + half];
        unsigned int pA = Hq32[(size_t)eA.x * 32 + cp];
        unsigned int pB = Hq32[(size_t)eB.x * 32 + cp];
        float wA0 = bf_lo(eA.y), wA1 = bf_hi(eA.y);
        float wB0 = bf_lo(eB.y), wB1 = bf_hi(eB.y);
        f32x2 heA = __builtin_amdgcn_cvt_pk_f32_fp8((int)pA, false);
        f32x2 hoA = __builtin_amdgcn_cvt_pk_f32_fp8((int)pA, true);
        f32x2 heB = __builtin_amdgcn_cvt_pk_f32_fp8((int)pB, false);
        f32x2 hoB = __builtin_amdgcn_cvt_pk_f32_fp8((int)pB, true);
        den0 += wA0 + wB0;
        den1 += wA1 + wB1;
        a00 += wA0 * heA[0] + wB0 * heB[0];
        a01 += wA1 * heA[1] + wB1 * heB[1];
        a10 += wA0 * hoA[0] + wB0 * hoB[0];
        a11 += wA1 * hoA[1] + wB1 * hoB[1];
    }
    if (j + 1 < end) {
        uint2 eA = erec[j + half];
        unsigned int pA = Hq32[(size_t)eA.x * 32 + cp];
        float wA0 = bf_lo(eA.y), wA1 = bf_hi(eA.y);
        f32x2 heA = __builtin_amdgcn_cvt_pk_f32_fp8((int)pA, false);
        f32x2 hoA = __builtin_amdgcn_cvt_pk_f32_fp8((int)pA, true);
        den0 += wA0;
        den1 += wA1;
        a00 += wA0 * heA[0];
        a01 += wA1 * heA[1];
        a10 += wA0 * hoA[0];
        a11 += wA1 * hoA[1];
        j += 2;
    }
    if (j < end && half == 0) {  // odd tail: only the even half processes it
        uint2 eA = erec[j];
        unsigned int pA = Hq32[(size_t)eA.x * 32 + cp];
        float wA0 = bf_lo(eA.y), wA1 = bf_hi(eA.y);
        f32x2 heA = __builtin_amdgcn_cvt_pk_f32_fp8((int)pA, false);
        f32x2 hoA = __builtin_amdgcn_cvt_pk_f32_fp8((int)pA, true);
        den0 += wA0;
        den1 += wA1;
        a00 += wA0 * heA[0];
        a01 += wA1 * heA[1];
        a10 += wA0 * hoA[0];
        a11 += wA1 * hoA[1];
    }
    a00 += __shfl_xor(a00, 32, 64);
    a01 += __shfl_xor(a01, 32, 64);
    a10 += __shfl_xor(a10, 32, 64);
    a11 += __shfl_xor(a11, 32, 64);
    den0 += __shfl_xor(den0, 32, 64);
    den1 += __shfl_xor(den1, 32, 64);
    if (half == 0) {
        float2 sv = *(const float2*)&skipsrc[(size_t)n * 64 + 2 * cp];
        if (bnsc) {  // identity skip from previous layer's pre-BN buffer
            sv.x = sv.x * bnsc[2 * cp] + bnsc[64 + 2 * cp];
            sv.y = sv.y * bnsc[2 * cp + 1] + bnsc[64 + 2 * cp + 1];
            sv.x = sv.x >= 0.f ? sv.x : 0.01f * sv.x;
            sv.y = sv.y >= 0.f ? sv.y : 0.01f * sv.y;
        }
        float2 bi = *(const float2*)&bias[2 * cp];
        float id0 = 1.f / (den0 + 1e-16f), id1 = 1.f / (den1 + 1e-16f);
        float2 o;
        o.x = 0.5f * (a00 * id0 + a01 * id1) + bi.x + sv.x;
        o.y = 0.5f * (a10 * id0 + a11 * id1) + bi.y + sv.y;
        *(float2*)&hraw[(size_t)n * 64 + 2 * cp] = o;
    }
}

__global__ void bn_stats(const float* __restrict__ x, float* __restrict__ sums) {
    __shared__ float ls[256], ls2[256];
    int t = threadIdx.x;
    int c = t & 63, q = t >> 6;
    float s = 0.f, s2 = 0.f;
    int rbeg = blockIdx.x * 512;
    for (int r = rbeg + q; r < rbeg + 512; r += 4) {
        if (r < NN) {
            float v = x[(size_t)r * 64 + c];
            s += v;
            s2 += v * v;
        }
    }
    ls[t] = s;
    ls2[t] = s2;
    __syncthreads();
    if (t < 64) {
        s = ls[t] + ls[t + 64] + ls[t + 128] + ls[t + 192];
        s2 = ls2[t] + ls2[t + 64] + ls2[t + 128] + ls2[t + 192];
        atomicAdd(&sums[c], s);
        atomicAdd(&sums[64 + c], s2);
    }
}

__global__ void bn_final(const float* __restrict__ sums, const float* __restrict__ g,
                         const float* __restrict__ be, float* __restrict__ sc_sh) {
    int c = threadIdx.x;
    if (c < 64) {
        float mu = sums[c] / (float)NN;
        float var = sums[64 + c] / (float)NN - mu * mu;
        float sc = g[c] * rsqrtf(var + 1e-5f);
        sc_sh[c] = sc;
        sc_sh[64 + c] = be[c] - mu * sc;
    }
}

// JK max over {input proj, lrelu(bn_k(hraw_k))} for k=0,1,2 in one pass.
__global__ void final_out(const float* __restrict__ jkproj, const float* __restrict__ hA,
                          const float* __restrict__ hB, const float* __restrict__ hC,
                          const float* __restrict__ bnAll, float* __restrict__ out) {
    int i = blockIdx.x * blockDim.x + threadIdx.x;
    if (i < NN * 64) {
        int c = i & 63;
        float v0 = hA[i] * bnAll[c] + bnAll[64 + c];
        float v1 = hB[i] * bnAll[128 + c] + bnAll[192 + c];
        float v2 = hC[i] * bnAll[256 + c] + bnAll[320 + c];
        v0 = v0 >= 0.f ? v0 : 0.01f * v0;
        v1 = v1 >= 0.f ? v1 : 0.01f * v1;
        v2 = v2 >= 0.f ? v2 : 0.01f * v2;
        out[i] = fmaxf(fmaxf(jkproj[i], v0), fmaxf(v1, v2));
    }
}

extern "C" void kernel_launch(void* const* d_in, const int* in_sizes, int n_in,
                              void* d_out, int out_size, void* d_ws, size_t ws_size,
                              hipStream_t stream) {
    const float* x = (const float*)d_in[0];
    const int* ei = (const int*)d_in[1];
    const int* e_src_idx = ei;
    const int* e_dst_idx = ei + NE;
    const float* W0 = (const float*)d_in[2];
    const float* as0 = (const float*)d_in[3];
    const float* ad0 = (const float*)d_in[4];
    const float* b0 = (const float*)d_in[5];
    const float* skip0 = (const float*)d_in[6];
    const float* g0 = (const float*)d_in[7];
    const float* be0 = (const float*)d_in[8];
    const float* W1 = (const float*)d_in[9];
    const float* as1 = (const float*)d_in[10];
    const float* ad1 = (const float*)d_in[11];
    const float* b1 = (const float*)d_in[12];
    const float* g1 = (const float*)d_in[13];
    const float* be1 = (const float*)d_in[14];
    const float* W2 = (const float*)d_in[15];
    const float* as2 = (const float*)d_in[16];
    const float* ad2 = (const float*)d_in[17];
    const float* b2 = (const float*)d_in[18];
    const float* g2 = (const float*)d_in[19];
    const float* be2 = (const float*)d_in[20];
    const float* projW = (const float*)d_in[21];
    const float* projb = (const float*)d_in[22];
    float* out = (float*)d_out;

    char* p = (char*)d_ws;
    auto alloc = [&](size_t bytes) {
        char* r = p;
        p += (bytes + 255) & ~(size_t)255;
        return r;
    };
    // bcount (196 ints) + bnsumAll (384 floats) share one zeroed buffer.
    int* zbuf = (int*)alloc((size_t)(196 + 384) * 4);
    int* bcount = zbuf;
    float* bnsumAll = (float*)(zbuf + 196);
    int* bbase = (int*)alloc((size_t)(NBUC + 1) * 4);
    int* bucket_cursor = (int*)alloc((size_t)NBUC * 4);
    int* offsets = (int*)alloc((size_t)(NN + 1) * 4);
    int* csr_src = (int*)alloc((size_t)NE * 4);
    int* csr_dst = (int*)alloc((size_t)NE * 4);
    uint2* erec = (uint2*)alloc((size_t)NE * 8);
    unsigned int* binned = (unsigned int*)alloc((size_t)NE * 4);
    unsigned int* h_q32 = (unsigned int*)alloc((size_t)NN * 32 * 4);
    unsigned int* e_srcpk = (unsigned int*)alloc((size_t)NN * 4);
    unsigned int* e_dstpk = (unsigned int*)alloc((size_t)NN * 4);
    float* skipx = (float*)alloc((size_t)NN * 64 * 4);
    float* jkproj = (float*)alloc((size_t)NN * 64 * 4);
    float* hrawA = (float*)alloc((size_t)NN * 64 * 4);
    float* hrawB = (float*)alloc((size_t)NN * 64 * 4);
    float* hrawC = (float*)alloc((size_t)NN * 64 * 4);
    unsigned short* Wtcat = (unsigned short*)alloc(256 * 128 * 2);
    unsigned short* Wt1 = (unsigned short*)alloc(128 * 64 * 2);
    unsigned short* Wt2 = (unsigned short*)alloc(128 * 64 * 2);
    float* bnscAll = (float*)alloc(3 * 128 * 4);
    if ((size_t)(p - (char*)d_ws) > ws_size) return;

    // ---- CSR by destination: bucket count -> scan -> bin -> LDS sort ----
    zero_u32<<<3, 256, 0, stream>>>((unsigned int*)zbuf, 196 + 384);
    bucket_count<<<NB_BIN, 256, 0, stream>>>(e_dst_idx, bcount);
    bucket_scan<<<1, 64, 0, stream>>>(bcount, bbase, bucket_cursor, offsets);
    bin_edges<<<NB_BIN, 256, 0, stream>>>(e_src_idx, e_dst_idx, bucket_cursor, binned);
    bucket_sort<<<NBUC, 256, 0, stream>>>(binned, bbase, offsets, csr_src, csr_dst);
    prep_weights<<<192, 256, 0, stream>>>(W0, skip0, projW, W1, W2, Wtcat, Wt1, Wt2);

    int gblocks = (NN + 63) / 64;  // 1563

    // ---- Layer 0 (one GEMM: h+scores | skip+proj) ----
    gemm_mfma<128, true, false><<<dim3(gblocks, 2), 256, 0, stream>>>(
        x, Wtcat, h_q32, skipx, jkproj, projb, nullptr, as0, ad0, e_srcpk, e_dstpk);
    edge_w<<<(NE + 255) / 256, 256, 0, stream>>>(csr_src, csr_dst, e_srcpk, e_dstpk, erec);
    aggregate<<<(NN + 3) / 4, 256, 0, stream>>>(offsets, erec, h_q32, skipx, nullptr, b0,
                                                hrawA);
    bn_stats<<<(NN + 511) / 512, 256, 0, stream>>>(hrawA, bnsumAll);
    bn_final<<<1, 64, 0, stream>>>(bnsumAll, g0, be0, bnscAll);

    // ---- Layer 1 ----
    gemm_mfma<64, false, true><<<dim3(gblocks, 1), 256, 0, stream>>>(
        hrawA, Wt1, h_q32, nullptr, nullptr, nullptr, bnscAll, as1, ad1, e_srcpk, e_dstpk);
    edge_w<<<(NE + 255) / 256, 256, 0, stream>>>(csr_src, csr_dst, e_srcpk, e_dstpk, erec);
    aggregate<<<(NN + 3) / 4, 256, 0, stream>>>(offsets, erec, h_q32, hrawA, bnscAll, b1,
                                                hrawB);
    bn_stats<<<(NN + 511) / 512, 256, 0, stream>>>(hrawB, bnsumAll + 128);
    bn_final<<<1, 64, 0, stream>>>(bnsumAll + 128, g1, be1, bnscAll + 128);

    // ---- Layer 2 ----
    gemm_mfma<64, false, true><<<dim3(gblocks, 1), 256, 0, stream>>>(
        hrawB, Wt2, h_q32, nullptr, nullptr, nullptr, bnscAll + 128, as2, ad2, e_srcpk,
        e_dstpk);
    edge_w<<<(NE + 255) / 256, 256, 0, stream>>>(csr_src, csr_dst, e_srcpk, e_dstpk, erec);
    aggregate<<<(NN + 3) / 4, 256, 0, stream>>>(offsets, erec, h_q32, hrawB, bnscAll + 128,
                                                b2, hrawC);
    bn_stats<<<(NN + 511) / 512, 256, 0, stream>>>(hrawC, bnsumAll + 256);
    bn_final<<<1, 64, 0, stream>>>(bnsumAll + 256, g2, be2, bnscAll + 256);

    final_out<<<(NN * 64 + 255) / 256, 256, 0, stream>>>(jkproj, hrawA, hrawB, hrawC,
                                                         bnscAll, out);
}